// Round 9
// baseline (1379.218 us; speedup 1.0000x reference)
//
#include <hip/hip_runtime.h>
#include <math.h>

#define HH 4
#define CC 140
#define HALF 160   // padded channel stride of activations

typedef __attribute__((ext_vector_type(8))) short short8;
typedef __attribute__((ext_vector_type(8))) _Float16 half8;
typedef __attribute__((ext_vector_type(4))) float f32x4;
typedef __attribute__((ext_vector_type(2))) _Float16 h2;
typedef unsigned short u16;

__device__ inline u16 f2h(float x) {
  union { _Float16 h; u16 u; } v; v.h = (_Float16)x; return v.u;
}
__device__ inline float h2f(u16 u) {
  union { _Float16 h; u16 u; } v; v.u = u; return (float)v.h;
}
__device__ inline h2 u2h2(unsigned u) {
  union { unsigned u; h2 h; } v; v.u = u; return v.h;
}

// ============================ fused CSR build (4 launches) ============================
__global__ __launch_bounds__(256) void k_zero_i32(int* __restrict__ p, int n) {
  int i = blockIdx.x * 256 + threadIdx.x;
  if (i < n) p[i] = 0;
}
__global__ __launch_bounds__(256) void k_hist_all(
    const int* __restrict__ e0, int nE0, const int* __restrict__ e1, int nE1,
    const int* __restrict__ e2, int nE2, const int* __restrict__ cl1, int n0,
    const int* __restrict__ cl2, int n1,
    int* __restrict__ c0, int* __restrict__ c1, int* __restrict__ c2,
    int* __restrict__ c3, int* __restrict__ c4) {
  int j = blockIdx.x * 256 + threadIdx.x;
  if (j < nE0) { atomicAdd(&c0[e0[nE0 + j]], 1); return; }
  j -= nE0;
  if (j < nE1) { atomicAdd(&c1[e1[nE1 + j]], 1); return; }
  j -= nE1;
  if (j < nE2) { atomicAdd(&c2[e2[nE2 + j]], 1); return; }
  j -= nE2;
  if (j < n0) { atomicAdd(&c3[cl1[j]], 1); return; }
  j -= n0;
  if (j < n1) { atomicAdd(&c4[cl2[j]], 1); }
}
__global__ __launch_bounds__(1024) void k_exscan5(
    int* __restrict__ c0, int n0, int* __restrict__ r0,
    int* __restrict__ c1, int n1, int* __restrict__ r1,
    int* __restrict__ c2, int n2, int* __restrict__ r2,
    int* __restrict__ c3, int n3, int* __restrict__ r3,
    int* __restrict__ c4, int n4, int* __restrict__ r4) {
  int* in; int n; int* out;
  switch (blockIdx.x) {
    case 0: in = c0; n = n0; out = r0; break;
    case 1: in = c1; n = n1; out = r1; break;
    case 2: in = c2; n = n2; out = r2; break;
    case 3: in = c3; n = n3; out = r3; break;
    default: in = c4; n = n4; out = r4; break;
  }
  __shared__ int buf[1024];
  __shared__ int carry_s;
  if (threadIdx.x == 0) carry_s = 0;
  __syncthreads();
  for (int base = 0; base < n; base += 1024) {
    int i = base + (int)threadIdx.x;
    int v = (i < n) ? in[i] : 0;
    buf[threadIdx.x] = v;
    __syncthreads();
    int x = v;
    for (int off = 1; off < 1024; off <<= 1) {
      int t = (threadIdx.x >= (unsigned)off) ? buf[threadIdx.x - off] : 0;
      __syncthreads();
      x += t;
      buf[threadIdx.x] = x;
      __syncthreads();
    }
    int carry = carry_s;
    if (i < n) {
      int pref = carry + x - v;
      out[i] = pref;
      in[i] = pref;
    }
    __syncthreads();
    if (threadIdx.x == 1023) carry_s = carry + buf[1023];
    __syncthreads();
  }
  if (threadIdx.x == 0) out[n] = carry_s;
}
__global__ __launch_bounds__(256) void k_scatter_all(
    const int* __restrict__ e0, int nE0, const int* __restrict__ e1, int nE1,
    const int* __restrict__ e2, int nE2, const int* __restrict__ cl1, int n0,
    const int* __restrict__ cl2, int n1,
    int* __restrict__ c0, int* __restrict__ c1, int* __restrict__ c2,
    int* __restrict__ c3, int* __restrict__ c4,
    int* __restrict__ s0, int* __restrict__ s1, int* __restrict__ s2,
    int* __restrict__ s3, int* __restrict__ s4) {
  int j = blockIdx.x * 256 + threadIdx.x;
  if (j < nE0) { int p = atomicAdd(&c0[e0[nE0 + j]], 1); s0[p] = e0[j]; return; }
  j -= nE0;
  if (j < nE1) { int p = atomicAdd(&c1[e1[nE1 + j]], 1); s1[p] = e1[j]; return; }
  j -= nE1;
  if (j < nE2) { int p = atomicAdd(&c2[e2[nE2 + j]], 1); s2[p] = e2[j]; return; }
  j -= nE2;
  if (j < n0) { int p = atomicAdd(&c3[cl1[j]], 1); s3[p] = j; return; }
  j -= n0;
  if (j < n1) { int p = atomicAdd(&c4[cl2[j]], 1); s4[p] = j; }
}

// ============================ pack1: GEMM1 [u|sW] mats + conv06 mat + xb ============================
#define S01 (192 * 32)
#define SS  (64 * 160)
#define SC  (192 * 320)
#define SO  (64 * 160)
__global__ __launch_bounds__(256) void k_pack1(
    const float* __restrict__ u01, const float* __restrict__ sW01,
    const float* __restrict__ us, const float* __restrict__ uc,
    const float* __restrict__ sWc,
    const float* __restrict__ Wo, const float* __restrict__ uo,
    const float* __restrict__ sWo, const float* __restrict__ x,
    u16* __restrict__ B01, u16* __restrict__ Bs10, u16* __restrict__ Bc2,
    u16* __restrict__ Bpo, u16* __restrict__ xb, int N0) {
  int j = blockIdx.x * 256 + threadIdx.x;
  if (j < S01) {  // conv01: [u(4)|sW(140)], K=4, Kpad=32, M=192
    int col = j / 32, kp = j % 32;
    float v = 0.f;
    if (kp < 4) {
      if (col < 4) v = u01[kp * 4 + col];
      else if (col < 144) v = sW01[kp * 140 + col - 4];
    }
    B01[j] = f2h(v);
    return;
  }
  j -= S01;
  if (j < 10 * SS) {  // identity: [u(4)], K=140, Kpad=160, M=64
    int r = j % SS, layer = j / SS;
    int col = r / 160, kp = r % 160;
    float v = 0.f;
    if (kp < 140 && col < 4) v = us[(size_t)layer * 560 + kp * 4 + col];
    Bs10[j] = f2h(v);
    return;
  }
  j -= 10 * SS;
  if (j < 2 * SC) {  // cat: [u(4)|sW(140)], K=280 split at 160, Kpad=320, M=192
    int layer = j / SC, r = j % SC;
    int col = r / 320, kp = r % 320;
    int ksrc = (kp < 140) ? kp : ((kp >= 160 && kp < 300) ? 140 + (kp - 160) : -1);
    float v = 0.f;
    if (ksrc >= 0) {
      if (col < 4) v = uc[(size_t)layer * 1120 + ksrc * 4 + col];
      else if (col < 144) v = sWc[(size_t)layer * 39200 + ksrc * 140 + col - 4];
    }
    Bc2[j] = f2h(v);
    return;
  }
  j -= 2 * SC;
  if (j < SO) {  // conv06: [Wo heads(4)|uo(4)|sWo(1)], K=140, Kpad=160, M=64
    int col = j / 160, kp = j % 160;
    float v = 0.f;
    if (kp < 140) {
      if (col < 4) v = Wo[kp * 4 + (col & 3)];
      else if (col < 8) v = uo[kp * 4 + (col - 4)];
      else if (col == 8) v = sWo[kp];
    }
    Bpo[j] = f2h(v);
    return;
  }
  j -= SO;
  if (j < N0 * 32) {
    int i = j >> 5, c = j & 31;
    xb[j] = f2h(c < 4 ? x[(size_t)i * 4 + c] : 0.f);
  }
}

// ============================ pack2: Wstack mats for GEMM2 ============================
#define T01 (160 * 32)
#define TS  (160 * 576)
#define TC  (160 * 1152)
__global__ __launch_bounds__(256) void k_pack2(
    const float* __restrict__ W01, const float* __restrict__ Ws,
    const float* __restrict__ Wc,
    u16* __restrict__ Q01, u16* __restrict__ Qs10, u16* __restrict__ Qc2) {
  int j = blockIdx.x * 256 + threadIdx.x;
  if (j < T01) {  // conv01: hs=8, K=4 per head
    int col = j / 32, kp = j % 32;
    int h = kp >> 3, kin = kp & 7;
    float v = (col < 140 && kin < 4) ? W01[kin * 560 + h * 140 + col] : 0.f;
    Q01[j] = f2h(v);
    return;
  }
  j -= T01;
  if (j < 10 * TS) {  // identity: hs=144
    int layer = j / TS, r = j % TS;
    int col = r / 576, kp = r % 576;
    int h = kp / 144, kin = kp % 144;
    float v = (col < 140 && kin < 140)
                  ? Ws[(size_t)layer * 78400 + (size_t)kin * 560 + h * 140 + col]
                  : 0.f;
    Qs10[j] = f2h(v);
    return;
  }
  j -= 10 * TS;
  if (j < 2 * TC) {  // cat: two halves of 576, hs=144; src row = kin or 140+kin
    int layer = j / TC, r = j % TC;
    int col = r / 1152, kp = r % 1152;
    int half = kp / 576, kph = kp % 576;
    int h = kph / 144, kin = kph % 144;
    int src = half ? 140 + kin : kin;
    float v = (col < 140 && kin < 140)
                  ? Wc[(size_t)layer * 156800 + (size_t)src * 560 + h * 140 + col]
                  : 0.f;
    Qc2[j] = f2h(v);
  }
}

// ============================ GEMM1 / conv06 GEMM (f16 MFMA, split out) ============================
//   gc < yEnd            -> Gy f16, row-stride yEnd
//   yEnd <= gc < yEnd+4  -> Gl f32 (logits)
//   yEnd+4 <= gc < +Cs   -> Gs f32, row-stride Cs (GEMM skip)
__global__ __launch_bounds__(256) void k_gemm_mfma(
    const u16* __restrict__ A1, const u16* __restrict__ A2,
    const int* __restrict__ amap, const u16* __restrict__ Bp,
    u16* __restrict__ Gy, float* __restrict__ Gl, float* __restrict__ Gs,
    int yEnd, int Cs, int N, int Kpad, int lda1) {
  __shared__ __align__(16) u16 As[128 * 32];
  __shared__ __align__(16) u16 Bs[64 * 32];
  const int tid = threadIdx.x;
  const int row0 = blockIdx.y * 128, col0 = blockIdx.x * 64;
  const int w = tid >> 6, lane = tid & 63;
  const int wm = w >> 1, wn = w & 1;
  const int arow = lane & 15, chunk = lane >> 4;
  const int swz = chunk ^ (arow & 3);
  f32x4 acc[4][2];
#pragma unroll
  for (int i = 0; i < 4; ++i)
#pragma unroll
    for (int j = 0; j < 2; ++j) acc[i][j] = (f32x4){0.f, 0.f, 0.f, 0.f};
  const int sar = tid >> 1;
  const int sak = (tid & 1) * 16;
  const int sbc = tid >> 2;
  const int sbk = (tid & 3) * 8;
  for (int k0 = 0; k0 < Kpad; k0 += 32) {
    {
      int gr = row0 + sar;
      short8 v0 = {0, 0, 0, 0, 0, 0, 0, 0}, v1 = v0;
      if (gr < N) {
        int kp0 = k0 + sak;
        const u16* b_;
        int rr, kk, ld;
        if (A2 && kp0 >= HALF) {
          b_ = A2; rr = gr; kk = kp0 - HALF; ld = HALF;
        } else {
          b_ = A1; rr = amap ? amap[gr] : gr; kk = kp0; ld = lda1;
        }
        const u16* p = b_ + (size_t)rr * ld + kk;
        v0 = *(const short8*)(p);
        v1 = *(const short8*)(p + 8);
      }
      int c0 = sak >> 3, sw = sar & 3;
      *(short8*)(As + sar * 32 + ((c0 ^ sw) << 3)) = v0;
      *(short8*)(As + sar * 32 + (((c0 + 1) ^ sw) << 3)) = v1;
    }
    {
      int gc = col0 + sbc;
      short8 v = *(const short8*)(Bp + (size_t)gc * Kpad + k0 + sbk);
      int c = sbk >> 3, sw = sbc & 3;
      *(short8*)(Bs + sbc * 32 + ((c ^ sw) << 3)) = v;
    }
    __syncthreads();
    half8 bf[2], af[4];
#pragma unroll
    for (int ni = 0; ni < 2; ++ni) {
      int col = wn * 32 + ni * 16 + arow;
      bf[ni] = *(const half8*)(Bs + col * 32 + (swz << 3));
    }
#pragma unroll
    for (int mi = 0; mi < 4; ++mi) {
      int r = wm * 64 + mi * 16 + arow;
      af[mi] = *(const half8*)(As + r * 32 + (swz << 3));
    }
#pragma unroll
    for (int mi = 0; mi < 4; ++mi)
#pragma unroll
      for (int ni = 0; ni < 2; ++ni)
        acc[mi][ni] = __builtin_amdgcn_mfma_f32_16x16x32_f16(af[mi], bf[ni], acc[mi][ni], 0, 0, 0);
    __syncthreads();
  }
  const int crow = (lane >> 4) * 4, ccol = lane & 15;
#pragma unroll
  for (int mi = 0; mi < 4; ++mi) {
    int gr0 = row0 + wm * 64 + mi * 16 + crow;
#pragma unroll
    for (int ni = 0; ni < 2; ++ni) {
      int gc = col0 + wn * 32 + ni * 16 + ccol;
#pragma unroll
      for (int j = 0; j < 4; ++j) {
        int gr = gr0 + j;
        if (gr >= N) continue;
        float v = acc[mi][ni][j];
        if (gc < yEnd) Gy[(size_t)gr * yEnd + gc] = f2h(v);
        else if (gc < yEnd + 4) Gl[(size_t)gr * 4 + (gc - yEnd)] = v;
        else if (gc < yEnd + 4 + Cs) Gs[(size_t)gr * Cs + (gc - yEnd - 4)] = v;
      }
    }
  }
}

// ============================ z-aggregation: z[d, h*hs+c] = sum_e q_h * x[src][c] ============================
__global__ __launch_bounds__(256) void k_aggz(
    const u16* __restrict__ X, int ldx, int Cin,
    const int* __restrict__ amap,
    const float* __restrict__ Gl, const float* __restrict__ cv,
    const int* __restrict__ rp, const int* __restrict__ sl,
    u16* __restrict__ z, int ldz, int hs,
    float* __restrict__ invd, int n) {
  int wid = blockIdx.x * 4 + ((int)threadIdx.x >> 6);
  int lane = threadIdx.x & 63;
  if (wid >= n) return;
  float4 la = *(const float4*)(Gl + (size_t)wid * 4);
  float d0 = cv[0] - la.x, d1 = cv[1] - la.y;
  float d2 = cv[2] - la.z, d3 = cv[3] - la.w;
  int eb = rp[wid], ee = rp[wid + 1];
  const int c0 = lane, c1 = lane + 64, c2 = lane + 128;
  float acc[4][3];
#pragma unroll
  for (int h = 0; h < 4; ++h)
#pragma unroll
    for (int s = 0; s < 3; ++s) acc[h][s] = 0.f;
  for (int base = eb; base < ee; base += 64) {
    int m = min(ee - base, 64);
    int rreg = 0, q01 = 0, q23 = 0;
    if (lane < m) {
      int s = sl[base + lane];
      rreg = amap ? amap[s] : s;
      float4 lg = *(const float4*)(Gl + (size_t)s * 4);
      float t0 = lg.x + d0, t1 = lg.y + d1, t2 = lg.z + d2, t3 = lg.w + d3;
      float mx = fmaxf(fmaxf(t0, t1), fmaxf(t2, t3));
      float q0 = __expf(t0 - mx), q1 = __expf(t1 - mx);
      float q2 = __expf(t2 - mx), q3 = __expf(t3 - mx);
      float qi = 1.f / (q0 + q1 + q2 + q3);
      q01 = (int)((unsigned)f2h(q0 * qi) | ((unsigned)f2h(q1 * qi) << 16));
      q23 = (int)((unsigned)f2h(q2 * qi) | ((unsigned)f2h(q3 * qi) << 16));
    }
#pragma unroll 2
    for (int j = 0; j < m; ++j) {
      int r = __shfl(rreg, j);
      h2 h01 = u2h2((unsigned)__shfl(q01, j));
      h2 h23 = u2h2((unsigned)__shfl(q23, j));
      float q0 = (float)h01[0], q1 = (float)h01[1];
      float q2 = (float)h23[0], q3 = (float)h23[1];
      const u16* xr = X + (size_t)r * ldx;
      float x0 = (c0 < Cin) ? h2f(xr[c0]) : 0.f;
      float x1 = (c1 < Cin) ? h2f(xr[c1]) : 0.f;
      float x2 = (c2 < Cin) ? h2f(xr[c2]) : 0.f;
      acc[0][0] += q0 * x0; acc[0][1] += q0 * x1; acc[0][2] += q0 * x2;
      acc[1][0] += q1 * x0; acc[1][1] += q1 * x1; acc[1][2] += q1 * x2;
      acc[2][0] += q2 * x0; acc[2][1] += q2 * x1; acc[2][2] += q2 * x2;
      acc[3][0] += q3 * x0; acc[3][1] += q3 * x1; acc[3][2] += q3 * x2;
    }
  }
  u16* zr = z + (size_t)wid * ldz;
#pragma unroll
  for (int h = 0; h < 4; ++h) {
    if (c0 < Cin) zr[h * hs + c0] = f2h(acc[h][0]);
    else if (c0 < hs) zr[h * hs + c0] = 0;
    if (c1 < Cin) zr[h * hs + c1] = f2h(acc[h][1]);
    else if (c1 < hs) zr[h * hs + c1] = 0;
    if (c2 < Cin) zr[h * hs + c2] = f2h(acc[h][2]);
    else if (c2 < hs) zr[h * hs + c2] = 0;
  }
  if (lane == 0) {
    int cnt = ee - eb;
    invd[wid] = 1.f / (float)(cnt > 1 ? cnt : 1);
  }
}

// ============================ GEMM2: out = z @ Wstack, fused /deg+bias+LN+skip+relu ============================
// BM=128 rows x BN=160 cols (full row in one block). 4 waves, each 32 rows x 160 cols.
__global__ __launch_bounds__(256) void k_gemm2(
    const u16* __restrict__ A1, const u16* __restrict__ A2, int lda,
    const u16* __restrict__ Bp, int Kpad,
    const float* __restrict__ invd, const float* __restrict__ bias,
    const float* __restrict__ g, const float* __restrict__ be,
    const u16* __restrict__ skipA, const float* __restrict__ Gs,
    const float* __restrict__ sb,
    u16* __restrict__ H, int n) {
  __shared__ __align__(16) u16 As[128 * 32];
  __shared__ __align__(16) u16 Bs[160 * 32];
  const int tid = threadIdx.x;
  const int row0 = blockIdx.x * 128;
  const int w = tid >> 6, lane = tid & 63;
  const int arow = lane & 15, chunk = lane >> 4;
  const int swz = chunk ^ (arow & 3);
  f32x4 acc[2][10];
#pragma unroll
  for (int mi = 0; mi < 2; ++mi)
#pragma unroll
    for (int ni = 0; ni < 10; ++ni) acc[mi][ni] = (f32x4){0.f, 0.f, 0.f, 0.f};
  const int sar = tid >> 1;
  const int sak = (tid & 1) * 16;
  for (int k0 = 0; k0 < Kpad; k0 += 32) {
    {
      int gr = row0 + sar;
      short8 v0 = {0, 0, 0, 0, 0, 0, 0, 0}, v1 = v0;
      if (gr < n) {
        int kp0 = k0 + sak;
        const u16* b_ = A1;
        int kk = kp0;
        if (A2 && kp0 >= 576) { b_ = A2; kk = kp0 - 576; }
        const u16* p = b_ + (size_t)gr * lda + kk;
        v0 = *(const short8*)(p);
        v1 = *(const short8*)(p + 8);
      }
      int c0 = sak >> 3, sw = sar & 3;
      *(short8*)(As + sar * 32 + ((c0 ^ sw) << 3)) = v0;
      *(short8*)(As + sar * 32 + (((c0 + 1) ^ sw) << 3)) = v1;
    }
#pragma unroll
    for (int it = 0; it < 3; ++it) {
      int i = tid + it * 256;
      if (i < 640) {
        int col = i >> 2, kf = (i & 3) * 8;
        short8 v = *(const short8*)(Bp + (size_t)col * Kpad + k0 + kf);
        *(short8*)(Bs + col * 32 + (((kf >> 3) ^ (col & 3)) << 3)) = v;
      }
    }
    __syncthreads();
    half8 af0, af1;
    {
      int r = w * 32 + arow;
      af0 = *(const half8*)(As + r * 32 + (swz << 3));
      af1 = *(const half8*)(As + (r + 16) * 32 + (swz << 3));
    }
#pragma unroll
    for (int ni = 0; ni < 10; ++ni) {
      int col = ni * 16 + arow;
      half8 bf = *(const half8*)(Bs + col * 32 + (swz << 3));
      acc[0][ni] = __builtin_amdgcn_mfma_f32_16x16x32_f16(af0, bf, acc[0][ni], 0, 0, 0);
      acc[1][ni] = __builtin_amdgcn_mfma_f32_16x16x32_f16(af1, bf, acc[1][ni], 0, 0, 0);
    }
    __syncthreads();
  }
  // ---- fused epilogue: /deg + bias + LN + skip + relu ----
  const int colL = arow, grp = lane >> 4;
  float bcol[10], gcol[10], becol[10], sbcol[10];
#pragma unroll
  for (int ni = 0; ni < 10; ++ni) {
    int c = ni * 16 + colL;
    bool ok = c < CC;
    bcol[ni] = ok ? bias[c] : 0.f;
    gcol[ni] = ok ? g[c] : 0.f;
    becol[ni] = ok ? be[c] : 0.f;
    sbcol[ni] = (sb != nullptr && ok) ? sb[c] : 0.f;
  }
#pragma unroll
  for (int mi = 0; mi < 2; ++mi) {
#pragma unroll
    for (int j = 0; j < 4; ++j) {
      int gr = row0 + w * 32 + mi * 16 + grp * 4 + j;
      bool rowok = gr < n;
      float iv = rowok ? invd[gr] : 0.f;
      float vals[10];
      float s1 = 0.f, s2 = 0.f;
#pragma unroll
      for (int ni = 0; ni < 10; ++ni) {
        float v = acc[mi][ni][j] * iv + bcol[ni];
        vals[ni] = v;
        s1 += v;
        s2 += v * v;
      }
      s1 += __shfl_xor(s1, 1); s2 += __shfl_xor(s2, 1);
      s1 += __shfl_xor(s1, 2); s2 += __shfl_xor(s2, 2);
      s1 += __shfl_xor(s1, 4); s2 += __shfl_xor(s2, 4);
      s1 += __shfl_xor(s1, 8); s2 += __shfl_xor(s2, 8);
      float mu = s1 * (1.0f / CC);
      float var = s2 * (1.0f / CC) - mu * mu;
      float rstd = rsqrtf(var + 1e-5f);
      if (rowok) {
#pragma unroll
        for (int ni = 0; ni < 10; ++ni) {
          int c = ni * 16 + colL;
          if (c < CC) {
            float v = (vals[ni] - mu) * rstd * gcol[ni] + becol[ni];
            float sk = skipA ? h2f(skipA[(size_t)gr * HALF + c])
                             : (Gs[(size_t)gr * CC + c] + sbcol[ni]);
            v = fmaxf(v + sk, 0.f);
            H[(size_t)gr * HALF + c] = f2h(v);
          } else {
            H[(size_t)gr * HALF + c] = 0;
          }
        }
      }
    }
  }
}

// ============================ conv06 edge kernel ============================
__global__ __launch_bounds__(256) void k_out(
    const u16* __restrict__ Gy, const float* __restrict__ Gl,
    const float* __restrict__ cv, const float* __restrict__ bo,
    const float* __restrict__ Gs, const float* __restrict__ sbo,
    const int* __restrict__ rp, const int* __restrict__ sl,
    float* __restrict__ out, int n) {
  int wid = blockIdx.x * 4 + ((int)threadIdx.x >> 6);
  int lane = threadIdx.x & 63;
  if (wid >= n) return;
  float4 la = *(const float4*)(Gl + (size_t)wid * 4);
  float d0 = cv[0] - la.x, d1 = cv[1] - la.y;
  float d2 = cv[2] - la.z, d3 = cv[3] - la.w;
  int eb = rp[wid], ee = rp[wid + 1];
  float part = 0.f;
  for (int e = eb + lane; e < ee; e += 64) {
    int s = sl[e];
    float4 lg = *(const float4*)(Gl + (size_t)s * 4);
    float t0 = lg.x + d0, t1 = lg.y + d1, t2 = lg.z + d2, t3 = lg.w + d3;
    float m = fmaxf(fmaxf(t0, t1), fmaxf(t2, t3));
    float q0 = __expf(t0 - m), q1 = __expf(t1 - m), q2 = __expf(t2 - m), q3 = __expf(t3 - m);
    float qi = 1.f / (q0 + q1 + q2 + q3);
    uint2 y = *(const uint2*)(Gy + (size_t)s * 4);
    h2 y01 = u2h2(y.x), y23 = u2h2(y.y);
    part += (q0 * (float)y01[0] + q1 * (float)y01[1] +
             q2 * (float)y23[0] + q3 * (float)y23[1]) * qi;
  }
#pragma unroll
  for (int off = 32; off > 0; off >>= 1) part += __shfl_xor(part, off);
  if (lane == 0) {
    int cnt = ee - eb;
    out[wid] = part / (float)(cnt > 1 ? cnt : 1) + bo[0] + Gs[wid] + sbo[0];
  }
}

// ============================ pool (f16 in/out) ============================
__global__ __launch_bounds__(256) void k_pool(const u16* __restrict__ inA,
                                              const int* __restrict__ rp,
                                              const int* __restrict__ sl,
                                              u16* __restrict__ outA, int nseg) {
  int wid = blockIdx.x * 4 + ((int)threadIdx.x >> 6);
  int lane = threadIdx.x & 63;
  if (wid >= nseg) return;
  int a = rp[wid], b = rp[wid + 1];
  const int c0 = lane, c1 = lane + 64, c2 = lane + 128;
  const bool h2v = c2 < CC;
  float acc0 = 0.f, acc1 = 0.f, acc2 = 0.f;
  for (int s = a; s < b; ++s) {
    size_t off = (size_t)sl[s] * HALF;
    acc0 += h2f(inA[off + c0]);
    acc1 += h2f(inA[off + c1]);
    if (h2v) acc2 += h2f(inA[off + c2]);
  }
  int cnt = b - a;
  float inv = 1.f / (float)(cnt > 1 ? cnt : 1);
  u16* oa = outA + (size_t)wid * HALF;
  oa[c0] = f2h(acc0 * inv);
  oa[c1] = f2h(acc1 * inv);
  if (h2v) oa[c2] = f2h(acc2 * inv);
  else if (c2 < HALF) oa[c2] = 0;
}

// ============================ host ============================
extern "C" void kernel_launch(void* const* d_in, const int* in_sizes, int n_in,
                              void* d_out, int out_size, void* d_ws, size_t ws_size,
                              hipStream_t stream) {
  (void)n_in; (void)out_size;
  const float* x    = (const float*)d_in[0];
  const int*   e0   = (const int*)d_in[1];
  const int*   e1   = (const int*)d_in[2];
  const int*   e2   = (const int*)d_in[3];
  const int*   cl1  = (const int*)d_in[4];
  const int*   cl2  = (const int*)d_in[5];
  const float* W01  = (const float*)d_in[9];
  const float* u01  = (const float*)d_in[10];
  const float* c01  = (const float*)d_in[11];
  const float* b01  = (const float*)d_in[12];
  const float* sW01 = (const float*)d_in[13];
  const float* sb01 = (const float*)d_in[14];
  const float* g01  = (const float*)d_in[15];
  const float* be01 = (const float*)d_in[16];
  const float* Ws   = (const float*)d_in[17];
  const float* us   = (const float*)d_in[18];
  const float* cs   = (const float*)d_in[19];
  const float* bs   = (const float*)d_in[20];
  const float* gs   = (const float*)d_in[21];
  const float* bes  = (const float*)d_in[22];
  const float* Wc   = (const float*)d_in[23];
  const float* uc   = (const float*)d_in[24];
  const float* cc   = (const float*)d_in[25];
  const float* bc   = (const float*)d_in[26];
  const float* sWc  = (const float*)d_in[27];
  const float* sbc  = (const float*)d_in[28];
  const float* gc   = (const float*)d_in[29];
  const float* bec  = (const float*)d_in[30];
  const float* Wo   = (const float*)d_in[31];
  const float* uo   = (const float*)d_in[32];
  const float* co   = (const float*)d_in[33];
  const float* bo   = (const float*)d_in[34];
  const float* sWo  = (const float*)d_in[35];
  const float* sbo  = (const float*)d_in[36];

  const int N0 = in_sizes[0] / 4;
  const int nE0 = in_sizes[1] / 2;
  const int nE1 = in_sizes[2] / 2;
  const int nE2 = in_sizes[3] / 2;
  const int N1 = 5000, N2 = 1250;

  // ---- workspace layout ----
  float* fp = (float*)d_ws;
  auto alloc_f = [&](size_t n) { n = (n + 15) & ~(size_t)15; float* p = fp; fp += n; return p; };
  auto alloc_h = [&](size_t n) { return (u16*)alloc_f((n + 1) / 2); };
  u16*   Gy = alloc_h((size_t)N0 * 8);
  float* Gl = alloc_f((size_t)N0 * 4);
  float* Gs = alloc_f((size_t)N0 * CC);
  float* invd = alloc_f((size_t)N0);
  u16* zA = alloc_h((size_t)N0 * 576);
  u16* zB = alloc_h((size_t)N0 * 576);
  u16* a0A = alloc_h((size_t)N0 * HALF);
  u16* a0B = alloc_h((size_t)N0 * HALF);
  u16* a1A = alloc_h((size_t)N1 * HALF);
  u16* a1B = alloc_h((size_t)N1 * HALF);
  u16* a2A = alloc_h((size_t)N2 * HALF);
  u16* a2B = alloc_h((size_t)N2 * HALF);
  u16* xb  = alloc_h((size_t)N0 * 32);
  u16* B01  = alloc_h(S01);
  u16* Bs10 = alloc_h((size_t)10 * SS);
  u16* Bc2  = alloc_h((size_t)2 * SC);
  u16* Bpo  = alloc_h(SO);
  u16* Q01  = alloc_h(T01);
  u16* Qs10 = alloc_h((size_t)10 * TS);
  u16* Qc2  = alloc_h((size_t)2 * TC);
  int* ipb = (int*)fp;
  auto alloc_i = [&](size_t n) { int* p = ipb; ipb += n; return p; };
  int* rp0  = alloc_i(N0 + 1);
  int* sl0  = alloc_i(nE0);
  int* rp1  = alloc_i(N1 + 1);
  int* sl1  = alloc_i(nE1);
  int* rp2  = alloc_i(N2 + 1);
  int* sl2  = alloc_i(nE2);
  int* rpc1 = alloc_i(N1 + 1);
  int* slc1 = alloc_i(N0);
  int* rpc2 = alloc_i(N2 + 1);
  int* slc2 = alloc_i(N1);
  int* cur0 = alloc_i(N0);
  int* cur1 = alloc_i(N1);
  int* cur2 = alloc_i(N2);
  int* cur3 = alloc_i(N1);
  int* cur4 = alloc_i(N2);
  const int curTot = N0 + N1 + N2 + N1 + N2;
  if ((size_t)((char*)ipb - (char*)d_ws) > ws_size) return;

  auto cdiv = [](int a, int b) { return (a + b - 1) / b; };

  // ---- CSR build ----
  k_zero_i32<<<cdiv(curTot, 256), 256, 0, stream>>>(cur0, curTot);
  {
    int tot = nE0 + nE1 + nE2 + N0 + N1;
    k_hist_all<<<cdiv(tot, 256), 256, 0, stream>>>(e0, nE0, e1, nE1, e2, nE2, cl1, N0, cl2, N1,
                                                   cur0, cur1, cur2, cur3, cur4);
    k_exscan5<<<5, 1024, 0, stream>>>(cur0, N0, rp0, cur1, N1, rp1, cur2, N2, rp2,
                                      cur3, N1, rpc1, cur4, N2, rpc2);
    k_scatter_all<<<cdiv(tot, 256), 256, 0, stream>>>(e0, nE0, e1, nE1, e2, nE2, cl1, N0, cl2, N1,
                                                      cur0, cur1, cur2, cur3, cur4,
                                                      sl0, sl1, sl2, slc1, slc2);
  }
  // ---- weight packs ----
  {
    int tot1 = S01 + 10 * SS + 2 * SC + SO + N0 * 32;
    k_pack1<<<cdiv(tot1, 256), 256, 0, stream>>>(u01, sW01, us, uc, sWc, Wo, uo, sWo, x,
                                                 B01, Bs10, Bc2, Bpo, xb, N0);
    int tot2 = T01 + 10 * TS + 2 * TC;
    k_pack2<<<cdiv(tot2, 256), 256, 0, stream>>>(W01, Ws, Wc, Q01, Qs10, Qc2);
  }

  auto ci  = [&](int i) { return cs + (size_t)i * HH; };
  auto bi  = [&](int i) { return bs + (size_t)i * CC; };
  auto gi  = [&](int i) { return gs + (size_t)i * CC; };
  auto bei = [&](int i) { return bes + (size_t)i * CC; };

  // identity conv: GEMM1(logits) + aggz + gemm2(identity skip)
  auto conv_plain = [&](const u16* aIn, const u16* Bp1, const u16* Bq, int n,
                        const int* rp, const int* sl, const float* cv,
                        const float* bp, const float* gp, const float* bep, u16* aOut) {
    dim3 g1(1, cdiv(n, 128));
    k_gemm_mfma<<<g1, 256, 0, stream>>>(aIn, nullptr, nullptr, Bp1, Gy, Gl, Gs,
                                        0, 0, n, 160, HALF);
    k_aggz<<<cdiv(n, 4), 256, 0, stream>>>(aIn, HALF, 140, nullptr, Gl, cv, rp, sl,
                                           zA, 576, 144, invd, n);
    k_gemm2<<<cdiv(n, 128), 256, 0, stream>>>(zA, nullptr, 576, Bq, 576, invd,
                                              bp, gp, bep, aIn, nullptr, nullptr, aOut, n);
  };

  // ---- conv01 ----
  {
    dim3 g1(3, cdiv(N0, 128));
    k_gemm_mfma<<<g1, 256, 0, stream>>>(xb, nullptr, nullptr, B01, Gy, Gl, Gs,
                                        0, 140, N0, 32, 32);
    k_aggz<<<cdiv(N0, 4), 256, 0, stream>>>(xb, 32, 4, nullptr, Gl, c01, rp0, sl0,
                                            zA, 32, 8, invd, N0);
    k_gemm2<<<cdiv(N0, 128), 256, 0, stream>>>(zA, nullptr, 32, Q01, 32, invd,
                                               b01, g01, be01, nullptr, Gs, sb01, a0A, N0);
  }
  // conv02 -> copy0 = a0B
  conv_plain(a0A, Bs10 + 0 * SS, Qs10 + (size_t)0 * TS, N0, rp0, sl0, ci(0), bi(0), gi(0), bei(0), a0B);
  // pool1
  k_pool<<<cdiv(N1, 4), 256, 0, stream>>>(a0B, rpc1, slc1, a1A, N1);
  // conv11, conv12 (copy1 = a1A)
  conv_plain(a1A, Bs10 + 1 * SS, Qs10 + (size_t)1 * TS, N1, rp1, sl1, ci(1), bi(1), gi(1), bei(1), a1B);
  conv_plain(a1B, Bs10 + 2 * SS, Qs10 + (size_t)2 * TS, N1, rp1, sl1, ci(2), bi(2), gi(2), bei(2), a1A);
  // pool2
  k_pool<<<cdiv(N2, 4), 256, 0, stream>>>(a1A, rpc2, slc2, a2A, N2);
  // conv21, conv22
  conv_plain(a2A, Bs10 + 3 * SS, Qs10 + (size_t)3 * TS, N2, rp2, sl2, ci(3), bi(3), gi(3), bei(3), a2B);
  conv_plain(a2B, Bs10 + 4 * SS, Qs10 + (size_t)4 * TS, N2, rp2, sl2, ci(4), bi(4), gi(4), bei(4), a2A);
  // ---- conv13: concat [unpool2(a2A) | a1A] ----
  {
    dim3 g1(3, cdiv(N1, 128));
    k_gemm_mfma<<<g1, 256, 0, stream>>>(a2A, a1A, cl2, Bc2 + 0 * SC, Gy, Gl, Gs,
                                        0, 140, N1, 320, HALF);
    k_aggz<<<cdiv(N1, 4), 256, 0, stream>>>(a2A, HALF, 140, cl2, Gl, cc, rp1, sl1,
                                            zA, 576, 144, invd, N1);
    k_aggz<<<cdiv(N1, 4), 256, 0, stream>>>(a1A, HALF, 140, nullptr, Gl, cc, rp1, sl1,
                                            zB, 576, 144, invd, N1);
    k_gemm2<<<cdiv(N1, 128), 256, 0, stream>>>(zA, zB, 576, Qc2 + (size_t)0 * TC, 1152, invd,
                                               bc, gc, bec, nullptr, Gs, sbc, a1B, N1);
  }
  // conv14, conv15, conv16
  conv_plain(a1B, Bs10 + 5 * SS, Qs10 + (size_t)5 * TS, N1, rp1, sl1, ci(5), bi(5), gi(5), bei(5), a1A);
  conv_plain(a1A, Bs10 + 6 * SS, Qs10 + (size_t)6 * TS, N1, rp1, sl1, ci(6), bi(6), gi(6), bei(6), a1B);
  conv_plain(a1B, Bs10 + 7 * SS, Qs10 + (size_t)7 * TS, N1, rp1, sl1, ci(7), bi(7), gi(7), bei(7), a1A);
  // ---- conv03: concat [unpool1(a1A) | a0B] ----
  {
    dim3 g1(3, cdiv(N0, 128));
    k_gemm_mfma<<<g1, 256, 0, stream>>>(a1A, a0B, cl1, Bc2 + 1 * SC, Gy, Gl, Gs,
                                        0, 140, N0, 320, HALF);
    k_aggz<<<cdiv(N0, 4), 256, 0, stream>>>(a1A, HALF, 140, cl1, Gl, cc + HH, rp0, sl0,
                                            zA, 576, 144, invd, N0);
    k_aggz<<<cdiv(N0, 4), 256, 0, stream>>>(a0B, HALF, 140, nullptr, Gl, cc + HH, rp0, sl0,
                                            zB, 576, 144, invd, N0);
    k_gemm2<<<cdiv(N0, 128), 256, 0, stream>>>(zA, zB, 576, Qc2 + (size_t)1 * TC, 1152, invd,
                                               bc + CC, gc + CC, bec + CC, nullptr, Gs, sbc + CC,
                                               a0A, N0);
  }
  // conv04, conv05
  conv_plain(a0A, Bs10 + 8 * SS, Qs10 + (size_t)8 * TS, N0, rp0, sl0, ci(8), bi(8), gi(8), bei(8), a0B);
  conv_plain(a0B, Bs10 + 9 * SS, Qs10 + (size_t)9 * TS, N0, rp0, sl0, ci(9), bi(9), gi(9), bei(9), a0A);
  // ---- conv06 ----
  {
    dim3 g1(1, cdiv(N0, 128));
    k_gemm_mfma<<<g1, 256, 0, stream>>>(a0A, nullptr, nullptr, Bpo, Gy, Gl, Gs,
                                        4, 1, N0, 160, HALF);
    k_out<<<cdiv(N0, 4), 256, 0, stream>>>(Gy, Gl, co, bo, Gs, sbo, rp0, sl0, (float*)d_out, N0);
  }
}

// Round 10
// 1093.795 us; speedup vs baseline: 1.2609x; 1.2609x over previous
//
#include <hip/hip_runtime.h>
#include <math.h>

#define HH 4
#define CC 140
#define HALF 160   // padded channel stride of activations

typedef __attribute__((ext_vector_type(8))) short short8;
typedef __attribute__((ext_vector_type(8))) _Float16 half8;
typedef __attribute__((ext_vector_type(4))) float f32x4;
typedef __attribute__((ext_vector_type(2))) _Float16 h2;
typedef unsigned short u16;

__device__ inline u16 f2h(float x) {
  union { _Float16 h; u16 u; } v; v.h = (_Float16)x; return v.u;
}
__device__ inline float h2f(u16 u) {
  union { _Float16 h; u16 u; } v; v.u = u; return (float)v.h;
}
__device__ inline h2 u2h2(unsigned u) {
  union { unsigned u; h2 h; } v; v.u = u; return v.h;
}

// ============================ fused CSR build (4 launches) ============================
__global__ __launch_bounds__(256) void k_zero_i32(int* __restrict__ p, int n) {
  int i = blockIdx.x * 256 + threadIdx.x;
  if (i < n) p[i] = 0;
}
__global__ __launch_bounds__(256) void k_hist_all(
    const int* __restrict__ e0, int nE0, const int* __restrict__ e1, int nE1,
    const int* __restrict__ e2, int nE2, const int* __restrict__ cl1, int n0,
    const int* __restrict__ cl2, int n1,
    int* __restrict__ c0, int* __restrict__ c1, int* __restrict__ c2,
    int* __restrict__ c3, int* __restrict__ c4) {
  int j = blockIdx.x * 256 + threadIdx.x;
  if (j < nE0) { atomicAdd(&c0[e0[nE0 + j]], 1); return; }
  j -= nE0;
  if (j < nE1) { atomicAdd(&c1[e1[nE1 + j]], 1); return; }
  j -= nE1;
  if (j < nE2) { atomicAdd(&c2[e2[nE2 + j]], 1); return; }
  j -= nE2;
  if (j < n0) { atomicAdd(&c3[cl1[j]], 1); return; }
  j -= n0;
  if (j < n1) { atomicAdd(&c4[cl2[j]], 1); }
}
__global__ __launch_bounds__(1024) void k_exscan5(
    int* __restrict__ c0, int n0, int* __restrict__ r0,
    int* __restrict__ c1, int n1, int* __restrict__ r1,
    int* __restrict__ c2, int n2, int* __restrict__ r2,
    int* __restrict__ c3, int n3, int* __restrict__ r3,
    int* __restrict__ c4, int n4, int* __restrict__ r4) {
  int* in; int n; int* out;
  switch (blockIdx.x) {
    case 0: in = c0; n = n0; out = r0; break;
    case 1: in = c1; n = n1; out = r1; break;
    case 2: in = c2; n = n2; out = r2; break;
    case 3: in = c3; n = n3; out = r3; break;
    default: in = c4; n = n4; out = r4; break;
  }
  __shared__ int buf[1024];
  __shared__ int carry_s;
  if (threadIdx.x == 0) carry_s = 0;
  __syncthreads();
  for (int base = 0; base < n; base += 1024) {
    int i = base + (int)threadIdx.x;
    int v = (i < n) ? in[i] : 0;
    buf[threadIdx.x] = v;
    __syncthreads();
    int x = v;
    for (int off = 1; off < 1024; off <<= 1) {
      int t = (threadIdx.x >= (unsigned)off) ? buf[threadIdx.x - off] : 0;
      __syncthreads();
      x += t;
      buf[threadIdx.x] = x;
      __syncthreads();
    }
    int carry = carry_s;
    if (i < n) {
      int pref = carry + x - v;
      out[i] = pref;
      in[i] = pref;
    }
    __syncthreads();
    if (threadIdx.x == 1023) carry_s = carry + buf[1023];
    __syncthreads();
  }
  if (threadIdx.x == 0) out[n] = carry_s;
}
__global__ __launch_bounds__(256) void k_scatter_all(
    const int* __restrict__ e0, int nE0, const int* __restrict__ e1, int nE1,
    const int* __restrict__ e2, int nE2, const int* __restrict__ cl1, int n0,
    const int* __restrict__ cl2, int n1,
    int* __restrict__ c0, int* __restrict__ c1, int* __restrict__ c2,
    int* __restrict__ c3, int* __restrict__ c4,
    int* __restrict__ s0, int* __restrict__ s1, int* __restrict__ s2,
    int* __restrict__ s3, int* __restrict__ s4) {
  int j = blockIdx.x * 256 + threadIdx.x;
  if (j < nE0) { int p = atomicAdd(&c0[e0[nE0 + j]], 1); s0[p] = e0[j]; return; }
  j -= nE0;
  if (j < nE1) { int p = atomicAdd(&c1[e1[nE1 + j]], 1); s1[p] = e1[j]; return; }
  j -= nE1;
  if (j < nE2) { int p = atomicAdd(&c2[e2[nE2 + j]], 1); s2[p] = e2[j]; return; }
  j -= nE2;
  if (j < n0) { int p = atomicAdd(&c3[cl1[j]], 1); s3[p] = j; return; }
  j -= n0;
  if (j < n1) { int p = atomicAdd(&c4[cl2[j]], 1); s4[p] = j; }
}

// ============================ pack1: GEMM1 [u|sW] mats + conv06 mat + xb ============================
#define S01 (192 * 32)
#define SS  (64 * 160)
#define SC  (192 * 320)
#define SO  (64 * 160)
__global__ __launch_bounds__(256) void k_pack1(
    const float* __restrict__ u01, const float* __restrict__ sW01,
    const float* __restrict__ us, const float* __restrict__ uc,
    const float* __restrict__ sWc,
    const float* __restrict__ Wo, const float* __restrict__ uo,
    const float* __restrict__ sWo, const float* __restrict__ x,
    u16* __restrict__ B01, u16* __restrict__ Bs10, u16* __restrict__ Bc2,
    u16* __restrict__ Bpo, u16* __restrict__ xb, int N0) {
  int j = blockIdx.x * 256 + threadIdx.x;
  if (j < S01) {  // conv01: [u(4)|sW(140)], K=4, Kpad=32, M=192
    int col = j / 32, kp = j % 32;
    float v = 0.f;
    if (kp < 4) {
      if (col < 4) v = u01[kp * 4 + col];
      else if (col < 144) v = sW01[kp * 140 + col - 4];
    }
    B01[j] = f2h(v);
    return;
  }
  j -= S01;
  if (j < 10 * SS) {  // identity: [u(4)], K=140, Kpad=160, M=64
    int r = j % SS, layer = j / SS;
    int col = r / 160, kp = r % 160;
    float v = 0.f;
    if (kp < 140 && col < 4) v = us[(size_t)layer * 560 + kp * 4 + col];
    Bs10[j] = f2h(v);
    return;
  }
  j -= 10 * SS;
  if (j < 2 * SC) {  // cat: [u(4)|sW(140)], K=280 split at 160, Kpad=320, M=192
    int layer = j / SC, r = j % SC;
    int col = r / 320, kp = r % 320;
    int ksrc = (kp < 140) ? kp : ((kp >= 160 && kp < 300) ? 140 + (kp - 160) : -1);
    float v = 0.f;
    if (ksrc >= 0) {
      if (col < 4) v = uc[(size_t)layer * 1120 + ksrc * 4 + col];
      else if (col < 144) v = sWc[(size_t)layer * 39200 + ksrc * 140 + col - 4];
    }
    Bc2[j] = f2h(v);
    return;
  }
  j -= 2 * SC;
  if (j < SO) {  // conv06: [Wo heads(4)|uo(4)|sWo(1)], K=140, Kpad=160, M=64
    int col = j / 160, kp = j % 160;
    float v = 0.f;
    if (kp < 140) {
      if (col < 4) v = Wo[kp * 4 + (col & 3)];
      else if (col < 8) v = uo[kp * 4 + (col - 4)];
      else if (col == 8) v = sWo[kp];
    }
    Bpo[j] = f2h(v);
    return;
  }
  j -= SO;
  if (j < N0 * 32) {
    int i = j >> 5, c = j & 31;
    xb[j] = f2h(c < 4 ? x[(size_t)i * 4 + c] : 0.f);
  }
}

// ============================ pack2: Wstack mats for GEMM2 ============================
#define T01 (160 * 32)
#define TS  (160 * 576)
#define TC  (160 * 1152)
__global__ __launch_bounds__(256) void k_pack2(
    const float* __restrict__ W01, const float* __restrict__ Ws,
    const float* __restrict__ Wc,
    u16* __restrict__ Q01, u16* __restrict__ Qs10, u16* __restrict__ Qc2) {
  int j = blockIdx.x * 256 + threadIdx.x;
  if (j < T01) {  // conv01: hs=8, K=4 per head
    int col = j / 32, kp = j % 32;
    int h = kp >> 3, kin = kp & 7;
    float v = (col < 140 && kin < 4) ? W01[kin * 560 + h * 140 + col] : 0.f;
    Q01[j] = f2h(v);
    return;
  }
  j -= T01;
  if (j < 10 * TS) {  // identity: hs=144
    int layer = j / TS, r = j % TS;
    int col = r / 576, kp = r % 576;
    int h = kp / 144, kin = kp % 144;
    float v = (col < 140 && kin < 140)
                  ? Ws[(size_t)layer * 78400 + (size_t)kin * 560 + h * 140 + col]
                  : 0.f;
    Qs10[j] = f2h(v);
    return;
  }
  j -= 10 * TS;
  if (j < 2 * TC) {  // cat: two halves of 576, hs=144; src row = kin or 140+kin
    int layer = j / TC, r = j % TC;
    int col = r / 1152, kp = r % 1152;
    int half = kp / 576, kph = kp % 576;
    int h = kph / 144, kin = kph % 144;
    int src = half ? 140 + kin : kin;
    float v = (col < 140 && kin < 140)
                  ? Wc[(size_t)layer * 156800 + (size_t)src * 560 + h * 140 + col]
                  : 0.f;
    Qc2[j] = f2h(v);
  }
}

// ============================ generic f16 MFMA GEMM, split output ============================
//   gc < yEnd            -> Gy f16, row-stride yEnd
//   yEnd <= gc < yEnd+4  -> Gl f32 (logits)
//   yEnd+4 <= gc < +Cs   -> Gs f32, row-stride Cs
// (yEnd=-4, Cs=160 => all 160 cols to Gs as raw f32 -- used for GEMM2)
// A row r: kp < split -> A1 at row (amap?amap[r]:r), stride lda1; else A2 at row r, stride lda2.
__global__ __launch_bounds__(256) void k_gemm_mfma(
    const u16* __restrict__ A1, const u16* __restrict__ A2,
    const int* __restrict__ amap, const u16* __restrict__ Bp,
    u16* __restrict__ Gy, float* __restrict__ Gl, float* __restrict__ Gs,
    int yEnd, int Cs, int N, int Kpad, int lda1, int split, int lda2) {
  __shared__ __align__(16) u16 As[128 * 32];
  __shared__ __align__(16) u16 Bs[64 * 32];
  const int tid = threadIdx.x;
  const int row0 = blockIdx.y * 128, col0 = blockIdx.x * 64;
  const int w = tid >> 6, lane = tid & 63;
  const int wm = w >> 1, wn = w & 1;
  const int arow = lane & 15, chunk = lane >> 4;
  const int swz = chunk ^ (arow & 3);
  f32x4 acc[4][2];
#pragma unroll
  for (int i = 0; i < 4; ++i)
#pragma unroll
    for (int j = 0; j < 2; ++j) acc[i][j] = (f32x4){0.f, 0.f, 0.f, 0.f};
  const int sar = tid >> 1;
  const int sak = (tid & 1) * 16;
  const int sbc = tid >> 2;
  const int sbk = (tid & 3) * 8;
  for (int k0 = 0; k0 < Kpad; k0 += 32) {
    {
      int gr = row0 + sar;
      short8 v0 = {0, 0, 0, 0, 0, 0, 0, 0}, v1 = v0;
      if (gr < N) {
        int kp0 = k0 + sak;
        const u16* b_;
        int rr, kk, ld;
        if (A2 && kp0 >= split) {
          b_ = A2; rr = gr; kk = kp0 - split; ld = lda2;
        } else {
          b_ = A1; rr = amap ? amap[gr] : gr; kk = kp0; ld = lda1;
        }
        const u16* p = b_ + (size_t)rr * ld + kk;
        v0 = *(const short8*)(p);
        v1 = *(const short8*)(p + 8);
      }
      int c0 = sak >> 3, sw = sar & 3;
      *(short8*)(As + sar * 32 + ((c0 ^ sw) << 3)) = v0;
      *(short8*)(As + sar * 32 + (((c0 + 1) ^ sw) << 3)) = v1;
    }
    {
      int gc = col0 + sbc;
      short8 v = *(const short8*)(Bp + (size_t)gc * Kpad + k0 + sbk);
      int c = sbk >> 3, sw = sbc & 3;
      *(short8*)(Bs + sbc * 32 + ((c ^ sw) << 3)) = v;
    }
    __syncthreads();
    half8 bf[2], af[4];
#pragma unroll
    for (int ni = 0; ni < 2; ++ni) {
      int col = wn * 32 + ni * 16 + arow;
      bf[ni] = *(const half8*)(Bs + col * 32 + (swz << 3));
    }
#pragma unroll
    for (int mi = 0; mi < 4; ++mi) {
      int r = wm * 64 + mi * 16 + arow;
      af[mi] = *(const half8*)(As + r * 32 + (swz << 3));
    }
#pragma unroll
    for (int mi = 0; mi < 4; ++mi)
#pragma unroll
      for (int ni = 0; ni < 2; ++ni)
        acc[mi][ni] = __builtin_amdgcn_mfma_f32_16x16x32_f16(af[mi], bf[ni], acc[mi][ni], 0, 0, 0);
    __syncthreads();
  }
  const int crow = (lane >> 4) * 4, ccol = lane & 15;
#pragma unroll
  for (int mi = 0; mi < 4; ++mi) {
    int gr0 = row0 + wm * 64 + mi * 16 + crow;
#pragma unroll
    for (int ni = 0; ni < 2; ++ni) {
      int gc = col0 + wn * 32 + ni * 16 + ccol;
#pragma unroll
      for (int j = 0; j < 4; ++j) {
        int gr = gr0 + j;
        if (gr >= N) continue;
        float v = acc[mi][ni][j];
        if (gc < yEnd) Gy[(size_t)gr * yEnd + gc] = f2h(v);
        else if (gc < yEnd + 4) Gl[(size_t)gr * 4 + (gc - yEnd)] = v;
        else if (gc < yEnd + 4 + Cs) Gs[(size_t)gr * Cs + (gc - yEnd - 4)] = v;
      }
    }
  }
}

// ============================ z-aggregation: z[d, h*hs+c] = sum_e q_h * x[src][c] ============================
__global__ __launch_bounds__(256) void k_aggz(
    const u16* __restrict__ X, int ldx, int Cin,
    const int* __restrict__ amap,
    const float* __restrict__ Gl, const float* __restrict__ cv,
    const int* __restrict__ rp, const int* __restrict__ sl,
    u16* __restrict__ z, int ldz, int hs,
    float* __restrict__ invd, int n) {
  int wid = blockIdx.x * 4 + ((int)threadIdx.x >> 6);
  int lane = threadIdx.x & 63;
  if (wid >= n) return;
  float4 la = *(const float4*)(Gl + (size_t)wid * 4);
  float d0 = cv[0] - la.x, d1 = cv[1] - la.y;
  float d2 = cv[2] - la.z, d3 = cv[3] - la.w;
  int eb = rp[wid], ee = rp[wid + 1];
  const int c0 = lane, c1 = lane + 64, c2 = lane + 128;
  float acc[4][3];
#pragma unroll
  for (int h = 0; h < 4; ++h)
#pragma unroll
    for (int s = 0; s < 3; ++s) acc[h][s] = 0.f;
  for (int base = eb; base < ee; base += 64) {
    int m = min(ee - base, 64);
    int rreg = 0, q01 = 0, q23 = 0;
    if (lane < m) {
      int s = sl[base + lane];
      rreg = amap ? amap[s] : s;
      float4 lg = *(const float4*)(Gl + (size_t)s * 4);
      float t0 = lg.x + d0, t1 = lg.y + d1, t2 = lg.z + d2, t3 = lg.w + d3;
      float mx = fmaxf(fmaxf(t0, t1), fmaxf(t2, t3));
      float q0 = __expf(t0 - mx), q1 = __expf(t1 - mx);
      float q2 = __expf(t2 - mx), q3 = __expf(t3 - mx);
      float qi = 1.f / (q0 + q1 + q2 + q3);
      q01 = (int)((unsigned)f2h(q0 * qi) | ((unsigned)f2h(q1 * qi) << 16));
      q23 = (int)((unsigned)f2h(q2 * qi) | ((unsigned)f2h(q3 * qi) << 16));
    }
#pragma unroll 2
    for (int j = 0; j < m; ++j) {
      int r = __shfl(rreg, j);
      h2 h01 = u2h2((unsigned)__shfl(q01, j));
      h2 h23 = u2h2((unsigned)__shfl(q23, j));
      float q0 = (float)h01[0], q1 = (float)h01[1];
      float q2 = (float)h23[0], q3 = (float)h23[1];
      const u16* xr = X + (size_t)r * ldx;
      float x0 = (c0 < Cin) ? h2f(xr[c0]) : 0.f;
      float x1 = (c1 < Cin) ? h2f(xr[c1]) : 0.f;
      float x2 = (c2 < Cin) ? h2f(xr[c2]) : 0.f;
      acc[0][0] += q0 * x0; acc[0][1] += q0 * x1; acc[0][2] += q0 * x2;
      acc[1][0] += q1 * x0; acc[1][1] += q1 * x1; acc[1][2] += q1 * x2;
      acc[2][0] += q2 * x0; acc[2][1] += q2 * x1; acc[2][2] += q2 * x2;
      acc[3][0] += q3 * x0; acc[3][1] += q3 * x1; acc[3][2] += q3 * x2;
    }
  }
  u16* zr = z + (size_t)wid * ldz;
#pragma unroll
  for (int h = 0; h < 4; ++h) {
    if (c0 < Cin) zr[h * hs + c0] = f2h(acc[h][0]);
    else if (c0 < hs) zr[h * hs + c0] = 0;
    if (c1 < Cin) zr[h * hs + c1] = f2h(acc[h][1]);
    else if (c1 < hs) zr[h * hs + c1] = 0;
    if (c2 < Cin) zr[h * hs + c2] = f2h(acc[h][2]);
    else if (c2 < hs) zr[h * hs + c2] = 0;
  }
  if (lane == 0) {
    int cnt = ee - eb;
    invd[wid] = 1.f / (float)(cnt > 1 ? cnt : 1);
  }
}

// ============================ post: /deg + bias + LN + skip + relu (wave per node) ============================
__global__ __launch_bounds__(256) void k_post(
    const float* __restrict__ Gw,      // (n,160) raw gemm2 out
    const float* __restrict__ invd,
    const float* __restrict__ bias, const float* __restrict__ g,
    const float* __restrict__ be,
    const u16* __restrict__ skipA,     // identity skip f16 (or null)
    const float* __restrict__ Gs, const float* __restrict__ sb,  // GEMM skip
    u16* __restrict__ outA, int n) {
  int wid = blockIdx.x * 4 + ((int)threadIdx.x >> 6);
  int lane = threadIdx.x & 63;
  if (wid >= n) return;
  const int c0 = lane, c1 = lane + 64, c2 = lane + 128;
  const bool h2v = c2 < CC;
  const float* gw = Gw + (size_t)wid * HALF;
  float iv = invd[wid];
  float v0 = gw[c0] * iv + bias[c0];
  float v1 = gw[c1] * iv + bias[c1];
  float v2 = h2v ? gw[c2] * iv + bias[c2] : 0.f;
  {
    float s1 = v0 + v1 + v2;
    float s2 = v0 * v0 + v1 * v1 + v2 * v2;
#pragma unroll
    for (int off = 32; off > 0; off >>= 1) {
      s1 += __shfl_xor(s1, off);
      s2 += __shfl_xor(s2, off);
    }
    float mu = s1 * (1.0f / CC);
    float var = s2 * (1.0f / CC) - mu * mu;
    float r = rsqrtf(var + 1e-5f);
    v0 = (v0 - mu) * r * g[c0] + be[c0];
    v1 = (v1 - mu) * r * g[c1] + be[c1];
    if (h2v) v2 = (v2 - mu) * r * g[c2] + be[c2];
  }
  if (skipA) {
    const u16* sk = skipA + (size_t)wid * HALF;
    v0 += h2f(sk[c0]);
    v1 += h2f(sk[c1]);
    if (h2v) v2 += h2f(sk[c2]);
  } else {
    const float* gsr = Gs + (size_t)wid * CC;
    v0 += gsr[c0] + sb[c0];
    v1 += gsr[c1] + sb[c1];
    if (h2v) v2 += gsr[c2] + sb[c2];
  }
  v0 = fmaxf(v0, 0.f);
  v1 = fmaxf(v1, 0.f);
  v2 = fmaxf(v2, 0.f);
  u16* oa = outA + (size_t)wid * HALF;
  oa[c0] = f2h(v0);
  oa[c1] = f2h(v1);
  if (h2v) oa[c2] = f2h(v2);
  else if (c2 < HALF) oa[c2] = 0;
}

// ============================ conv06 edge kernel ============================
__global__ __launch_bounds__(256) void k_out(
    const u16* __restrict__ Gy, const float* __restrict__ Gl,
    const float* __restrict__ cv, const float* __restrict__ bo,
    const float* __restrict__ Gs, const float* __restrict__ sbo,
    const int* __restrict__ rp, const int* __restrict__ sl,
    float* __restrict__ out, int n) {
  int wid = blockIdx.x * 4 + ((int)threadIdx.x >> 6);
  int lane = threadIdx.x & 63;
  if (wid >= n) return;
  float4 la = *(const float4*)(Gl + (size_t)wid * 4);
  float d0 = cv[0] - la.x, d1 = cv[1] - la.y;
  float d2 = cv[2] - la.z, d3 = cv[3] - la.w;
  int eb = rp[wid], ee = rp[wid + 1];
  float part = 0.f;
  for (int e = eb + lane; e < ee; e += 64) {
    int s = sl[e];
    float4 lg = *(const float4*)(Gl + (size_t)s * 4);
    float t0 = lg.x + d0, t1 = lg.y + d1, t2 = lg.z + d2, t3 = lg.w + d3;
    float m = fmaxf(fmaxf(t0, t1), fmaxf(t2, t3));
    float q0 = __expf(t0 - m), q1 = __expf(t1 - m), q2 = __expf(t2 - m), q3 = __expf(t3 - m);
    float qi = 1.f / (q0 + q1 + q2 + q3);
    uint2 y = *(const uint2*)(Gy + (size_t)s * 4);
    h2 y01 = u2h2(y.x), y23 = u2h2(y.y);
    part += (q0 * (float)y01[0] + q1 * (float)y01[1] +
             q2 * (float)y23[0] + q3 * (float)y23[1]) * qi;
  }
#pragma unroll
  for (int off = 32; off > 0; off >>= 1) part += __shfl_xor(part, off);
  if (lane == 0) {
    int cnt = ee - eb;
    out[wid] = part / (float)(cnt > 1 ? cnt : 1) + bo[0] + Gs[wid] + sbo[0];
  }
}

// ============================ pool (f16 in/out) ============================
__global__ __launch_bounds__(256) void k_pool(const u16* __restrict__ inA,
                                              const int* __restrict__ rp,
                                              const int* __restrict__ sl,
                                              u16* __restrict__ outA, int nseg) {
  int wid = blockIdx.x * 4 + ((int)threadIdx.x >> 6);
  int lane = threadIdx.x & 63;
  if (wid >= nseg) return;
  int a = rp[wid], b = rp[wid + 1];
  const int c0 = lane, c1 = lane + 64, c2 = lane + 128;
  const bool h2v = c2 < CC;
  float acc0 = 0.f, acc1 = 0.f, acc2 = 0.f;
  for (int s = a; s < b; ++s) {
    size_t off = (size_t)sl[s] * HALF;
    acc0 += h2f(inA[off + c0]);
    acc1 += h2f(inA[off + c1]);
    if (h2v) acc2 += h2f(inA[off + c2]);
  }
  int cnt = b - a;
  float inv = 1.f / (float)(cnt > 1 ? cnt : 1);
  u16* oa = outA + (size_t)wid * HALF;
  oa[c0] = f2h(acc0 * inv);
  oa[c1] = f2h(acc1 * inv);
  if (h2v) oa[c2] = f2h(acc2 * inv);
  else if (c2 < HALF) oa[c2] = 0;
}

// ============================ host ============================
extern "C" void kernel_launch(void* const* d_in, const int* in_sizes, int n_in,
                              void* d_out, int out_size, void* d_ws, size_t ws_size,
                              hipStream_t stream) {
  (void)n_in; (void)out_size;
  const float* x    = (const float*)d_in[0];
  const int*   e0   = (const int*)d_in[1];
  const int*   e1   = (const int*)d_in[2];
  const int*   e2   = (const int*)d_in[3];
  const int*   cl1  = (const int*)d_in[4];
  const int*   cl2  = (const int*)d_in[5];
  const float* W01  = (const float*)d_in[9];
  const float* u01  = (const float*)d_in[10];
  const float* c01  = (const float*)d_in[11];
  const float* b01  = (const float*)d_in[12];
  const float* sW01 = (const float*)d_in[13];
  const float* sb01 = (const float*)d_in[14];
  const float* g01  = (const float*)d_in[15];
  const float* be01 = (const float*)d_in[16];
  const float* Ws   = (const float*)d_in[17];
  const float* us   = (const float*)d_in[18];
  const float* cs   = (const float*)d_in[19];
  const float* bs   = (const float*)d_in[20];
  const float* gs   = (const float*)d_in[21];
  const float* bes  = (const float*)d_in[22];
  const float* Wc   = (const float*)d_in[23];
  const float* uc   = (const float*)d_in[24];
  const float* cc   = (const float*)d_in[25];
  const float* bc   = (const float*)d_in[26];
  const float* sWc  = (const float*)d_in[27];
  const float* sbc  = (const float*)d_in[28];
  const float* gc   = (const float*)d_in[29];
  const float* bec  = (const float*)d_in[30];
  const float* Wo   = (const float*)d_in[31];
  const float* uo   = (const float*)d_in[32];
  const float* co   = (const float*)d_in[33];
  const float* bo   = (const float*)d_in[34];
  const float* sWo  = (const float*)d_in[35];
  const float* sbo  = (const float*)d_in[36];

  const int N0 = in_sizes[0] / 4;
  const int nE0 = in_sizes[1] / 2;
  const int nE1 = in_sizes[2] / 2;
  const int nE2 = in_sizes[3] / 2;
  const int N1 = 5000, N2 = 1250;

  // ---- workspace layout ----
  float* fp = (float*)d_ws;
  auto alloc_f = [&](size_t n) { n = (n + 15) & ~(size_t)15; float* p = fp; fp += n; return p; };
  auto alloc_h = [&](size_t n) { return (u16*)alloc_f((n + 1) / 2); };
  u16*   Gy = alloc_h((size_t)N0 * 8);
  float* Gl = alloc_f((size_t)N0 * 4);
  float* Gs = alloc_f((size_t)N0 * CC);
  float* Gw = alloc_f((size_t)N0 * HALF);
  float* invd = alloc_f((size_t)N0);
  u16* zA = alloc_h((size_t)N0 * 576);
  u16* zB = alloc_h((size_t)N0 * 576);
  u16* a0A = alloc_h((size_t)N0 * HALF);
  u16* a0B = alloc_h((size_t)N0 * HALF);
  u16* a1A = alloc_h((size_t)N1 * HALF);
  u16* a1B = alloc_h((size_t)N1 * HALF);
  u16* a2A = alloc_h((size_t)N2 * HALF);
  u16* a2B = alloc_h((size_t)N2 * HALF);
  u16* xb  = alloc_h((size_t)N0 * 32);
  u16* B01  = alloc_h(S01);
  u16* Bs10 = alloc_h((size_t)10 * SS);
  u16* Bc2  = alloc_h((size_t)2 * SC);
  u16* Bpo  = alloc_h(SO);
  u16* Q01  = alloc_h(T01);
  u16* Qs10 = alloc_h((size_t)10 * TS);
  u16* Qc2  = alloc_h((size_t)2 * TC);
  u16* Qpad = alloc_h((size_t)64 * 1152);  // OOB-read pad for col-blocks past M
  (void)Qpad;
  int* ipb = (int*)fp;
  auto alloc_i = [&](size_t n) { int* p = ipb; ipb += n; return p; };
  int* rp0  = alloc_i(N0 + 1);
  int* sl0  = alloc_i(nE0);
  int* rp1  = alloc_i(N1 + 1);
  int* sl1  = alloc_i(nE1);
  int* rp2  = alloc_i(N2 + 1);
  int* sl2  = alloc_i(nE2);
  int* rpc1 = alloc_i(N1 + 1);
  int* slc1 = alloc_i(N0);
  int* rpc2 = alloc_i(N2 + 1);
  int* slc2 = alloc_i(N1);
  int* cur0 = alloc_i(N0);
  int* cur1 = alloc_i(N1);
  int* cur2 = alloc_i(N2);
  int* cur3 = alloc_i(N1);
  int* cur4 = alloc_i(N2);
  const int curTot = N0 + N1 + N2 + N1 + N2;
  if ((size_t)((char*)ipb - (char*)d_ws) > ws_size) return;

  auto cdiv = [](int a, int b) { return (a + b - 1) / b; };

  // ---- CSR build ----
  k_zero_i32<<<cdiv(curTot, 256), 256, 0, stream>>>(cur0, curTot);
  {
    int tot = nE0 + nE1 + nE2 + N0 + N1;
    k_hist_all<<<cdiv(tot, 256), 256, 0, stream>>>(e0, nE0, e1, nE1, e2, nE2, cl1, N0, cl2, N1,
                                                   cur0, cur1, cur2, cur3, cur4);
    k_exscan5<<<5, 1024, 0, stream>>>(cur0, N0, rp0, cur1, N1, rp1, cur2, N2, rp2,
                                      cur3, N1, rpc1, cur4, N2, rpc2);
    k_scatter_all<<<cdiv(tot, 256), 256, 0, stream>>>(e0, nE0, e1, nE1, e2, nE2, cl1, N0, cl2, N1,
                                                      cur0, cur1, cur2, cur3, cur4,
                                                      sl0, sl1, sl2, slc1, slc2);
  }
  // ---- weight packs ----
  {
    int tot1 = S01 + 10 * SS + 2 * SC + SO + N0 * 32;
    k_pack1<<<cdiv(tot1, 256), 256, 0, stream>>>(u01, sW01, us, uc, sWc, Wo, uo, sWo, x,
                                                 B01, Bs10, Bc2, Bpo, xb, N0);
    int tot2 = T01 + 10 * TS + 2 * TC;
    k_pack2<<<cdiv(tot2, 256), 256, 0, stream>>>(W01, Ws, Wc, Q01, Qs10, Qc2);
  }

  auto ci  = [&](int i) { return cs + (size_t)i * HH; };
  auto bi  = [&](int i) { return bs + (size_t)i * CC; };
  auto gi  = [&](int i) { return gs + (size_t)i * CC; };
  auto bei = [&](int i) { return bes + (size_t)i * CC; };

  // identity conv: GEMM1(logits) + aggz + GEMM2(->Gw) + post(identity skip)
  auto conv_plain = [&](const u16* aIn, const u16* Bp1, const u16* Bq, int n,
                        const int* rp, const int* sl, const float* cv,
                        const float* bp, const float* gp, const float* bep, u16* aOut) {
    dim3 g1(1, cdiv(n, 128));
    k_gemm_mfma<<<g1, 256, 0, stream>>>(aIn, nullptr, nullptr, Bp1, Gy, Gl, Gs,
                                        0, 0, n, 160, HALF, HALF, HALF);
    k_aggz<<<cdiv(n, 4), 256, 0, stream>>>(aIn, HALF, 140, nullptr, Gl, cv, rp, sl,
                                           zA, 576, 144, invd, n);
    dim3 g2(3, cdiv(n, 128));
    k_gemm_mfma<<<g2, 256, 0, stream>>>(zA, nullptr, nullptr, Bq, Gy, Gl, Gw,
                                        -4, 160, n, 576, 576, HALF, HALF);
    k_post<<<cdiv(n, 4), 256, 0, stream>>>(Gw, invd, bp, gp, bep, aIn, nullptr, nullptr,
                                           aOut, n);
  };

  // ---- conv01 ----
  {
    dim3 g1(3, cdiv(N0, 128));
    k_gemm_mfma<<<g1, 256, 0, stream>>>(xb, nullptr, nullptr, B01, Gy, Gl, Gs,
                                        0, 140, N0, 32, 32, HALF, HALF);
    k_aggz<<<cdiv(N0, 4), 256, 0, stream>>>(xb, 32, 4, nullptr, Gl, c01, rp0, sl0,
                                            zA, 32, 8, invd, N0);
    dim3 g2(3, cdiv(N0, 128));
    k_gemm_mfma<<<g2, 256, 0, stream>>>(zA, nullptr, nullptr, Q01, Gy, Gl, Gw,
                                        -4, 160, N0, 32, 32, HALF, HALF);
    k_post<<<cdiv(N0, 4), 256, 0, stream>>>(Gw, invd, b01, g01, be01, nullptr, Gs, sb01,
                                            a0A, N0);
  }
  // conv02 -> copy0 = a0B
  conv_plain(a0A, Bs10 + 0 * SS, Qs10 + (size_t)0 * TS, N0, rp0, sl0, ci(0), bi(0), gi(0), bei(0), a0B);
  // pool1
  k_pool<<<cdiv(N1, 4), 256, 0, stream>>>(a0B, rpc1, slc1, a1A, N1);
  // conv11, conv12 (copy1 = a1A)
  conv_plain(a1A, Bs10 + 1 * SS, Qs10 + (size_t)1 * TS, N1, rp1, sl1, ci(1), bi(1), gi(1), bei(1), a1B);
  conv_plain(a1B, Bs10 + 2 * SS, Qs10 + (size_t)2 * TS, N1, rp1, sl1, ci(2), bi(2), gi(2), bei(2), a1A);
  // pool2
  k_pool<<<cdiv(N2, 4), 256, 0, stream>>>(a1A, rpc2, slc2, a2A, N2);
  // conv21, conv22
  conv_plain(a2A, Bs10 + 3 * SS, Qs10 + (size_t)3 * TS, N2, rp2, sl2, ci(3), bi(3), gi(3), bei(3), a2B);
  conv_plain(a2B, Bs10 + 4 * SS, Qs10 + (size_t)4 * TS, N2, rp2, sl2, ci(4), bi(4), gi(4), bei(4), a2A);
  // ---- conv13: concat [unpool2(a2A) | a1A] ----
  {
    dim3 g1(3, cdiv(N1, 128));
    k_gemm_mfma<<<g1, 256, 0, stream>>>(a2A, a1A, cl2, Bc2 + 0 * SC, Gy, Gl, Gs,
                                        0, 140, N1, 320, HALF, HALF, HALF);
    k_aggz<<<cdiv(N1, 4), 256, 0, stream>>>(a2A, HALF, 140, cl2, Gl, cc, rp1, sl1,
                                            zA, 576, 144, invd, N1);
    k_aggz<<<cdiv(N1, 4), 256, 0, stream>>>(a1A, HALF, 140, nullptr, Gl, cc, rp1, sl1,
                                            zB, 576, 144, invd, N1);
    dim3 g2(3, cdiv(N1, 128));
    k_gemm_mfma<<<g2, 256, 0, stream>>>(zA, zB, nullptr, Qc2 + (size_t)0 * TC, Gy, Gl, Gw,
                                        -4, 160, N1, 1152, 576, 576, 576);
    k_post<<<cdiv(N1, 4), 256, 0, stream>>>(Gw, invd, bc, gc, bec, nullptr, Gs, sbc,
                                            a1B, N1);
  }
  // conv14, conv15, conv16
  conv_plain(a1B, Bs10 + 5 * SS, Qs10 + (size_t)5 * TS, N1, rp1, sl1, ci(5), bi(5), gi(5), bei(5), a1A);
  conv_plain(a1A, Bs10 + 6 * SS, Qs10 + (size_t)6 * TS, N1, rp1, sl1, ci(6), bi(6), gi(6), bei(6), a1B);
  conv_plain(a1B, Bs10 + 7 * SS, Qs10 + (size_t)7 * TS, N1, rp1, sl1, ci(7), bi(7), gi(7), bei(7), a1A);
  // ---- conv03: concat [unpool1(a1A) | a0B] ----
  {
    dim3 g1(3, cdiv(N0, 128));
    k_gemm_mfma<<<g1, 256, 0, stream>>>(a1A, a0B, cl1, Bc2 + 1 * SC, Gy, Gl, Gs,
                                        0, 140, N0, 320, HALF, HALF, HALF);
    k_aggz<<<cdiv(N0, 4), 256, 0, stream>>>(a1A, HALF, 140, cl1, Gl, cc + HH, rp0, sl0,
                                            zA, 576, 144, invd, N0);
    k_aggz<<<cdiv(N0, 4), 256, 0, stream>>>(a0B, HALF, 140, nullptr, Gl, cc + HH, rp0, sl0,
                                            zB, 576, 144, invd, N0);
    dim3 g2(3, cdiv(N0, 128));
    k_gemm_mfma<<<g2, 256, 0, stream>>>(zA, zB, nullptr, Qc2 + (size_t)1 * TC, Gy, Gl, Gw,
                                        -4, 160, N0, 1152, 576, 576, 576);
    k_post<<<cdiv(N0, 4), 256, 0, stream>>>(Gw, invd, bc + CC, gc + CC, bec + CC, nullptr,
                                            Gs, sbc + CC, a0A, N0);
  }
  // conv04, conv05
  conv_plain(a0A, Bs10 + 8 * SS, Qs10 + (size_t)8 * TS, N0, rp0, sl0, ci(8), bi(8), gi(8), bei(8), a0B);
  conv_plain(a0B, Bs10 + 9 * SS, Qs10 + (size_t)9 * TS, N0, rp0, sl0, ci(9), bi(9), gi(9), bei(9), a0A);
  // ---- conv06 ----
  {
    dim3 g1(1, cdiv(N0, 128));
    k_gemm_mfma<<<g1, 256, 0, stream>>>(a0A, nullptr, nullptr, Bpo, Gy, Gl, Gs,
                                        4, 1, N0, 160, HALF, HALF, HALF);
    k_out<<<cdiv(N0, 4), 256, 0, stream>>>(Gy, Gl, co, bo, Gs, sbo, rp0, sl0, (float*)d_out, N0);
  }
}

// Round 11
// 848.348 us; speedup vs baseline: 1.6258x; 1.2893x over previous
//
#include <hip/hip_runtime.h>
#include <math.h>

#define HH 4
#define CC 140
#define HALF 160   // padded channel stride of activations

typedef __attribute__((ext_vector_type(8))) short short8;
typedef __attribute__((ext_vector_type(8))) _Float16 half8;
typedef __attribute__((ext_vector_type(4))) float f32x4;
typedef __attribute__((ext_vector_type(2))) _Float16 h2;
typedef unsigned short u16;

__device__ inline u16 f2h(float x) {
  union { _Float16 h; u16 u; } v; v.h = (_Float16)x; return v.u;
}
__device__ inline float h2f(u16 u) {
  union { _Float16 h; u16 u; } v; v.u = u; return (float)v.h;
}
__device__ inline h2 u2h2(unsigned u) {
  union { unsigned u; h2 h; } v; v.u = u; return v.h;
}

// ============================ fused CSR build (4 launches) ============================
__global__ __launch_bounds__(256) void k_zero_i32(int* __restrict__ p, int n) {
  int i = blockIdx.x * 256 + threadIdx.x;
  if (i < n) p[i] = 0;
}
__global__ __launch_bounds__(256) void k_hist_all(
    const int* __restrict__ e0, int nE0, const int* __restrict__ e1, int nE1,
    const int* __restrict__ e2, int nE2, const int* __restrict__ cl1, int n0,
    const int* __restrict__ cl2, int n1,
    int* __restrict__ c0, int* __restrict__ c1, int* __restrict__ c2,
    int* __restrict__ c3, int* __restrict__ c4) {
  int j = blockIdx.x * 256 + threadIdx.x;
  if (j < nE0) { atomicAdd(&c0[e0[nE0 + j]], 1); return; }
  j -= nE0;
  if (j < nE1) { atomicAdd(&c1[e1[nE1 + j]], 1); return; }
  j -= nE1;
  if (j < nE2) { atomicAdd(&c2[e2[nE2 + j]], 1); return; }
  j -= nE2;
  if (j < n0) { atomicAdd(&c3[cl1[j]], 1); return; }
  j -= n0;
  if (j < n1) { atomicAdd(&c4[cl2[j]], 1); }
}
__global__ __launch_bounds__(1024) void k_exscan5(
    int* __restrict__ c0, int n0, int* __restrict__ r0,
    int* __restrict__ c1, int n1, int* __restrict__ r1,
    int* __restrict__ c2, int n2, int* __restrict__ r2,
    int* __restrict__ c3, int n3, int* __restrict__ r3,
    int* __restrict__ c4, int n4, int* __restrict__ r4) {
  int* in; int n; int* out;
  switch (blockIdx.x) {
    case 0: in = c0; n = n0; out = r0; break;
    case 1: in = c1; n = n1; out = r1; break;
    case 2: in = c2; n = n2; out = r2; break;
    case 3: in = c3; n = n3; out = r3; break;
    default: in = c4; n = n4; out = r4; break;
  }
  __shared__ int buf[1024];
  __shared__ int carry_s;
  if (threadIdx.x == 0) carry_s = 0;
  __syncthreads();
  for (int base = 0; base < n; base += 1024) {
    int i = base + (int)threadIdx.x;
    int v = (i < n) ? in[i] : 0;
    buf[threadIdx.x] = v;
    __syncthreads();
    int x = v;
    for (int off = 1; off < 1024; off <<= 1) {
      int t = (threadIdx.x >= (unsigned)off) ? buf[threadIdx.x - off] : 0;
      __syncthreads();
      x += t;
      buf[threadIdx.x] = x;
      __syncthreads();
    }
    int carry = carry_s;
    if (i < n) {
      int pref = carry + x - v;
      out[i] = pref;
      in[i] = pref;
    }
    __syncthreads();
    if (threadIdx.x == 1023) carry_s = carry + buf[1023];
    __syncthreads();
  }
  if (threadIdx.x == 0) out[n] = carry_s;
}
__global__ __launch_bounds__(256) void k_scatter_all(
    const int* __restrict__ e0, int nE0, const int* __restrict__ e1, int nE1,
    const int* __restrict__ e2, int nE2, const int* __restrict__ cl1, int n0,
    const int* __restrict__ cl2, int n1,
    int* __restrict__ c0, int* __restrict__ c1, int* __restrict__ c2,
    int* __restrict__ c3, int* __restrict__ c4,
    int* __restrict__ s0, int* __restrict__ s1, int* __restrict__ s2,
    int* __restrict__ s3, int* __restrict__ s4) {
  int j = blockIdx.x * 256 + threadIdx.x;
  if (j < nE0) { int p = atomicAdd(&c0[e0[nE0 + j]], 1); s0[p] = e0[j]; return; }
  j -= nE0;
  if (j < nE1) { int p = atomicAdd(&c1[e1[nE1 + j]], 1); s1[p] = e1[j]; return; }
  j -= nE1;
  if (j < nE2) { int p = atomicAdd(&c2[e2[nE2 + j]], 1); s2[p] = e2[j]; return; }
  j -= nE2;
  if (j < n0) { int p = atomicAdd(&c3[cl1[j]], 1); s3[p] = j; return; }
  j -= n0;
  if (j < n1) { int p = atomicAdd(&c4[cl2[j]], 1); s4[p] = j; }
}

// ============================ pack1: conv01/cat/conv06 GEMM1 mats + xb ============================
#define S01 (192 * 32)
#define SC  (192 * 320)
#define SO  (64 * 160)
__global__ __launch_bounds__(256) void k_pack1(
    const float* __restrict__ u01, const float* __restrict__ sW01,
    const float* __restrict__ uc, const float* __restrict__ sWc,
    const float* __restrict__ Wo, const float* __restrict__ uo,
    const float* __restrict__ sWo, const float* __restrict__ x,
    u16* __restrict__ B01, u16* __restrict__ Bc2,
    u16* __restrict__ Bpo, u16* __restrict__ xb, int N0) {
  int j = blockIdx.x * 256 + threadIdx.x;
  if (j < S01) {  // conv01: [u(4)|sW(140)], K=4, Kpad=32, M=192
    int col = j / 32, kp = j % 32;
    float v = 0.f;
    if (kp < 4) {
      if (col < 4) v = u01[kp * 4 + col];
      else if (col < 144) v = sW01[kp * 140 + col - 4];
    }
    B01[j] = f2h(v);
    return;
  }
  j -= S01;
  if (j < 2 * SC) {  // cat: [u(4)|sW(140)], K=280 split at 160, Kpad=320, M=192
    int layer = j / SC, r = j % SC;
    int col = r / 320, kp = r % 320;
    int ksrc = (kp < 140) ? kp : ((kp >= 160 && kp < 300) ? 140 + (kp - 160) : -1);
    float v = 0.f;
    if (ksrc >= 0) {
      if (col < 4) v = uc[(size_t)layer * 1120 + ksrc * 4 + col];
      else if (col < 144) v = sWc[(size_t)layer * 39200 + ksrc * 140 + col - 4];
    }
    Bc2[j] = f2h(v);
    return;
  }
  j -= 2 * SC;
  if (j < SO) {  // conv06: [Wo heads(4)|uo(4)|sWo(1)], K=140, Kpad=160, M=64
    int col = j / 160, kp = j % 160;
    float v = 0.f;
    if (kp < 140) {
      if (col < 4) v = Wo[kp * 4 + (col & 3)];
      else if (col < 8) v = uo[kp * 4 + (col - 4)];
      else if (col == 8) v = sWo[kp];
    }
    Bpo[j] = f2h(v);
    return;
  }
  j -= SO;
  if (j < N0 * 32) {
    int i = j >> 5, c = j & 31;
    xb[j] = f2h(c < 4 ? x[(size_t)i * 4 + c] : 0.f);
  }
}

// ============================ pack2: Wstack mats for GEMM2 ============================
#define T01 (160 * 32)
#define TS  (160 * 576)
#define TC  (160 * 1152)
__global__ __launch_bounds__(256) void k_pack2(
    const float* __restrict__ W01, const float* __restrict__ Ws,
    const float* __restrict__ Wc,
    u16* __restrict__ Q01, u16* __restrict__ Qs10, u16* __restrict__ Qc2) {
  int j = blockIdx.x * 256 + threadIdx.x;
  if (j < T01) {  // conv01: hs=8, K=4 per head
    int col = j / 32, kp = j % 32;
    int h = kp >> 3, kin = kp & 7;
    float v = (col < 140 && kin < 4) ? W01[kin * 560 + h * 140 + col] : 0.f;
    Q01[j] = f2h(v);
    return;
  }
  j -= T01;
  if (j < 10 * TS) {  // identity: hs=144
    int layer = j / TS, r = j % TS;
    int col = r / 576, kp = r % 576;
    int h = kp / 144, kin = kp % 144;
    float v = (col < 140 && kin < 140)
                  ? Ws[(size_t)layer * 78400 + (size_t)kin * 560 + h * 140 + col]
                  : 0.f;
    Qs10[j] = f2h(v);
    return;
  }
  j -= 10 * TS;
  if (j < 2 * TC) {  // cat: two halves of 576, hs=144
    int layer = j / TC, r = j % TC;
    int col = r / 1152, kp = r % 1152;
    int half = kp / 576, kph = kp % 576;
    int h = kph / 144, kin = kph % 144;
    int src = half ? 140 + kin : kin;
    float v = (col < 140 && kin < 140)
                  ? Wc[(size_t)layer * 156800 + (size_t)src * 560 + h * 140 + col]
                  : 0.f;
    Qc2[j] = f2h(v);
  }
}

// ============================ generic f16 MFMA GEMM, split output ============================
__global__ __launch_bounds__(256) void k_gemm_mfma(
    const u16* __restrict__ A1, const u16* __restrict__ A2,
    const int* __restrict__ amap, const u16* __restrict__ Bp,
    u16* __restrict__ Gy, float* __restrict__ Gl, float* __restrict__ Gs,
    int yEnd, int Cs, int N, int Kpad, int lda1, int split, int lda2) {
  __shared__ __align__(16) u16 As[128 * 32];
  __shared__ __align__(16) u16 Bs[64 * 32];
  const int tid = threadIdx.x;
  const int row0 = blockIdx.y * 128, col0 = blockIdx.x * 64;
  const int w = tid >> 6, lane = tid & 63;
  const int wm = w >> 1, wn = w & 1;
  const int arow = lane & 15, chunk = lane >> 4;
  const int swz = chunk ^ (arow & 3);
  f32x4 acc[4][2];
#pragma unroll
  for (int i = 0; i < 4; ++i)
#pragma unroll
    for (int j = 0; j < 2; ++j) acc[i][j] = (f32x4){0.f, 0.f, 0.f, 0.f};
  const int sar = tid >> 1;
  const int sak = (tid & 1) * 16;
  const int sbc = tid >> 2;
  const int sbk = (tid & 3) * 8;
  for (int k0 = 0; k0 < Kpad; k0 += 32) {
    {
      int gr = row0 + sar;
      short8 v0 = {0, 0, 0, 0, 0, 0, 0, 0}, v1 = v0;
      if (gr < N) {
        int kp0 = k0 + sak;
        const u16* b_;
        int rr, kk, ld;
        if (A2 && kp0 >= split) {
          b_ = A2; rr = gr; kk = kp0 - split; ld = lda2;
        } else {
          b_ = A1; rr = amap ? amap[gr] : gr; kk = kp0; ld = lda1;
        }
        const u16* p = b_ + (size_t)rr * ld + kk;
        v0 = *(const short8*)(p);
        v1 = *(const short8*)(p + 8);
      }
      int c0 = sak >> 3, sw = sar & 3;
      *(short8*)(As + sar * 32 + ((c0 ^ sw) << 3)) = v0;
      *(short8*)(As + sar * 32 + (((c0 + 1) ^ sw) << 3)) = v1;
    }
    {
      int gc = col0 + sbc;
      short8 v = *(const short8*)(Bp + (size_t)gc * Kpad + k0 + sbk);
      int c = sbk >> 3, sw = sbc & 3;
      *(short8*)(Bs + sbc * 32 + ((c ^ sw) << 3)) = v;
    }
    __syncthreads();
    half8 bf[2], af[4];
#pragma unroll
    for (int ni = 0; ni < 2; ++ni) {
      int col = wn * 32 + ni * 16 + arow;
      bf[ni] = *(const half8*)(Bs + col * 32 + (swz << 3));
    }
#pragma unroll
    for (int mi = 0; mi < 4; ++mi) {
      int r = wm * 64 + mi * 16 + arow;
      af[mi] = *(const half8*)(As + r * 32 + (swz << 3));
    }
#pragma unroll
    for (int mi = 0; mi < 4; ++mi)
#pragma unroll
      for (int ni = 0; ni < 2; ++ni)
        acc[mi][ni] = __builtin_amdgcn_mfma_f32_16x16x32_f16(af[mi], bf[ni], acc[mi][ni], 0, 0, 0);
    __syncthreads();
  }
  const int crow = (lane >> 4) * 4, ccol = lane & 15;
#pragma unroll
  for (int mi = 0; mi < 4; ++mi) {
    int gr0 = row0 + wm * 64 + mi * 16 + crow;
#pragma unroll
    for (int ni = 0; ni < 2; ++ni) {
      int gc = col0 + wn * 32 + ni * 16 + ccol;
#pragma unroll
      for (int j = 0; j < 4; ++j) {
        int gr = gr0 + j;
        if (gr >= N) continue;
        float v = acc[mi][ni][j];
        if (gc < yEnd) Gy[(size_t)gr * yEnd + gc] = f2h(v);
        else if (gc < yEnd + 4) Gl[(size_t)gr * 4 + (gc - yEnd)] = v;
        else if (gc < yEnd + 4 + Cs) Gs[(size_t)gr * Cs + (gc - yEnd - 4)] = v;
      }
    }
  }
}

// ============================ z-aggregation (pair-channel, batch-8 MLP) ============================
// z[d, h*hs+c] = sum_e q_h(e) * X[src_e][c].  Lane owns channels {2l,2l+1} + tail 128+l.
__global__ __launch_bounds__(256) void k_aggz(
    const u16* __restrict__ X, int ldx, int Cin,
    const int* __restrict__ amap,
    const float* __restrict__ Gl, const float* __restrict__ cv,
    const int* __restrict__ rp, const int* __restrict__ sl,
    u16* __restrict__ z, int ldz, int hs,
    float* __restrict__ invd, int n) {
  int wid = blockIdx.x * 4 + ((int)threadIdx.x >> 6);
  int lane = threadIdx.x & 63;
  if (wid >= n) return;
  float4 la = *(const float4*)(Gl + (size_t)wid * 4);
  float d0 = cv[0] - la.x, d1 = cv[1] - la.y;
  float d2 = cv[2] - la.z, d3 = cv[3] - la.w;
  int eb = rp[wid], ee = rp[wid + 1];
  const int cp = lane * 2;
  const int ct = 128 + lane;
  const bool pv = cp < Cin;
  const bool tv = ct < Cin;
  float aA0 = 0.f, aA1 = 0.f, aA2 = 0.f, aA3 = 0.f;
  float aB0 = 0.f, aB1 = 0.f, aB2 = 0.f, aB3 = 0.f;
  float aT0 = 0.f, aT1 = 0.f, aT2 = 0.f, aT3 = 0.f;
  for (int base = eb; base < ee; base += 64) {
    int m = min(ee - base, 64);
    int rreg = 0, q01 = 0, q23 = 0;
    if (lane < m) {
      int s = sl[base + lane];
      rreg = amap ? amap[s] : s;
      float4 lg = *(const float4*)(Gl + (size_t)s * 4);
      float t0 = lg.x + d0, t1 = lg.y + d1, t2 = lg.z + d2, t3 = lg.w + d3;
      float mx = fmaxf(fmaxf(t0, t1), fmaxf(t2, t3));
      float q0 = __expf(t0 - mx), q1 = __expf(t1 - mx);
      float q2 = __expf(t2 - mx), q3 = __expf(t3 - mx);
      float qi = 1.f / (q0 + q1 + q2 + q3);
      q01 = (int)((unsigned)f2h(q0 * qi) | ((unsigned)f2h(q1 * qi) << 16));
      q23 = (int)((unsigned)f2h(q2 * qi) | ((unsigned)f2h(q3 * qi) << 16));
    }
    for (int jb = 0; jb < m; jb += 8) {
      unsigned xv[8], p01[8], p23[8];
      u16 xt[8];
#pragma unroll
      for (int t = 0; t < 8; ++t) {
        int j = jb + t;
        int r = __shfl(rreg, j);
        unsigned a = (unsigned)__shfl(q01, j);
        unsigned b = (unsigned)__shfl(q23, j);
        bool v = j < m;
        p01[t] = v ? a : 0u;
        p23[t] = v ? b : 0u;
        const u16* xr = X + (size_t)r * ldx;
        xv[t] = (v && pv) ? *(const unsigned*)(xr + cp) : 0u;
        xt[t] = (v && tv) ? xr[ct] : (u16)0;
      }
#pragma unroll
      for (int t = 0; t < 8; ++t) {
        h2 xp = u2h2(xv[t]);
        float x0 = (float)xp[0], x1 = (float)xp[1];
        float x2 = h2f(xt[t]);
        h2 qa = u2h2(p01[t]), qb = u2h2(p23[t]);
        float q0 = (float)qa[0], q1 = (float)qa[1];
        float q2 = (float)qb[0], q3 = (float)qb[1];
        aA0 += q0 * x0; aB0 += q0 * x1; aT0 += q0 * x2;
        aA1 += q1 * x0; aB1 += q1 * x1; aT1 += q1 * x2;
        aA2 += q2 * x0; aB2 += q2 * x1; aT2 += q2 * x2;
        aA3 += q3 * x0; aB3 += q3 * x1; aT3 += q3 * x2;
      }
    }
  }
  u16* zr = z + (size_t)wid * ldz;
  float pA[4] = {aA0, aA1, aA2, aA3};
  float pB[4] = {aB0, aB1, aB2, aB3};
  float pT[4] = {aT0, aT1, aT2, aT3};
#pragma unroll
  for (int h = 0; h < 4; ++h) {
    if (cp < hs) {
      unsigned wv = pv ? ((unsigned)f2h(pA[h]) | ((unsigned)f2h(pB[h]) << 16)) : 0u;
      *(unsigned*)(zr + h * hs + cp) = wv;
    }
    if (lane < 16 && ct < hs) {
      zr[h * hs + ct] = tv ? f2h(pT[h]) : (u16)0;
    }
  }
  if (lane == 0) {
    int cnt = ee - eb;
    invd[wid] = 1.f / (float)(cnt > 1 ? cnt : 1);
  }
}

// ============================ post: /deg+bias+LN+skip+relu (+ next-layer logits) ============================
__global__ __launch_bounds__(256) void k_post(
    const float* __restrict__ Gw, const float* __restrict__ invd,
    const float* __restrict__ bias, const float* __restrict__ g,
    const float* __restrict__ be,
    const u16* __restrict__ skipA,
    const float* __restrict__ Gs, const float* __restrict__ sb,
    const float* __restrict__ uN, float* __restrict__ GlOut,
    u16* __restrict__ outA, int n) {
  int wid = blockIdx.x * 4 + ((int)threadIdx.x >> 6);
  int lane = threadIdx.x & 63;
  if (wid >= n) return;
  const int c0 = lane, c1 = lane + 64, c2 = lane + 128;
  const bool h2v = c2 < CC;
  const float* gw = Gw + (size_t)wid * HALF;
  float iv = invd[wid];
  float v0 = gw[c0] * iv + bias[c0];
  float v1 = gw[c1] * iv + bias[c1];
  float v2 = h2v ? gw[c2] * iv + bias[c2] : 0.f;
  {
    float s1 = v0 + v1 + v2;
    float s2 = v0 * v0 + v1 * v1 + v2 * v2;
#pragma unroll
    for (int off = 32; off > 0; off >>= 1) {
      s1 += __shfl_xor(s1, off);
      s2 += __shfl_xor(s2, off);
    }
    float mu = s1 * (1.0f / CC);
    float var = s2 * (1.0f / CC) - mu * mu;
    float r = rsqrtf(var + 1e-5f);
    v0 = (v0 - mu) * r * g[c0] + be[c0];
    v1 = (v1 - mu) * r * g[c1] + be[c1];
    if (h2v) v2 = (v2 - mu) * r * g[c2] + be[c2];
  }
  if (skipA) {
    const u16* sk = skipA + (size_t)wid * HALF;
    v0 += h2f(sk[c0]);
    v1 += h2f(sk[c1]);
    if (h2v) v2 += h2f(sk[c2]);
  } else {
    const float* gsr = Gs + (size_t)wid * CC;
    v0 += gsr[c0] + sb[c0];
    v1 += gsr[c1] + sb[c1];
    if (h2v) v2 += gsr[c2] + sb[c2];
  }
  v0 = fmaxf(v0, 0.f);
  v1 = fmaxf(v1, 0.f);
  v2 = fmaxf(v2, 0.f);
  u16* oa = outA + (size_t)wid * HALF;
  oa[c0] = f2h(v0);
  oa[c1] = f2h(v1);
  if (h2v) oa[c2] = f2h(v2);
  else if (c2 < HALF) oa[c2] = 0;
  if (uN) {
    float4 ua = *(const float4*)(uN + c0 * 4);
    float4 ub = *(const float4*)(uN + c1 * 4);
    float lx = v0 * ua.x + v1 * ub.x;
    float ly = v0 * ua.y + v1 * ub.y;
    float lz = v0 * ua.z + v1 * ub.z;
    float lw = v0 * ua.w + v1 * ub.w;
    if (h2v) {
      float4 uc_ = *(const float4*)(uN + c2 * 4);
      lx += v2 * uc_.x; ly += v2 * uc_.y; lz += v2 * uc_.z; lw += v2 * uc_.w;
    }
#pragma unroll
    for (int off = 32; off > 0; off >>= 1) {
      lx += __shfl_xor(lx, off);
      ly += __shfl_xor(ly, off);
      lz += __shfl_xor(lz, off);
      lw += __shfl_xor(lw, off);
    }
    if (lane == 0) {
      float* gl = GlOut + (size_t)wid * 4;
      gl[0] = lx; gl[1] = ly; gl[2] = lz; gl[3] = lw;
    }
  }
}

// ============================ conv06 edge kernel ============================
__global__ __launch_bounds__(256) void k_out(
    const u16* __restrict__ Gy, const float* __restrict__ Gl,
    const float* __restrict__ cv, const float* __restrict__ bo,
    const float* __restrict__ Gs, const float* __restrict__ sbo,
    const int* __restrict__ rp, const int* __restrict__ sl,
    float* __restrict__ out, int n) {
  int wid = blockIdx.x * 4 + ((int)threadIdx.x >> 6);
  int lane = threadIdx.x & 63;
  if (wid >= n) return;
  float4 la = *(const float4*)(Gl + (size_t)wid * 4);
  float d0 = cv[0] - la.x, d1 = cv[1] - la.y;
  float d2 = cv[2] - la.z, d3 = cv[3] - la.w;
  int eb = rp[wid], ee = rp[wid + 1];
  float part = 0.f;
  for (int e = eb + lane; e < ee; e += 64) {
    int s = sl[e];
    float4 lg = *(const float4*)(Gl + (size_t)s * 4);
    float t0 = lg.x + d0, t1 = lg.y + d1, t2 = lg.z + d2, t3 = lg.w + d3;
    float m = fmaxf(fmaxf(t0, t1), fmaxf(t2, t3));
    float q0 = __expf(t0 - m), q1 = __expf(t1 - m), q2 = __expf(t2 - m), q3 = __expf(t3 - m);
    float qi = 1.f / (q0 + q1 + q2 + q3);
    uint2 y = *(const uint2*)(Gy + (size_t)s * 4);
    h2 y01 = u2h2(y.x), y23 = u2h2(y.y);
    part += (q0 * (float)y01[0] + q1 * (float)y01[1] +
             q2 * (float)y23[0] + q3 * (float)y23[1]) * qi;
  }
#pragma unroll
  for (int off = 32; off > 0; off >>= 1) part += __shfl_xor(part, off);
  if (lane == 0) {
    int cnt = ee - eb;
    out[wid] = part / (float)(cnt > 1 ? cnt : 1) + bo[0] + Gs[wid] + sbo[0];
  }
}

// ============================ pool (f16 in/out, + next-layer logits) ============================
__global__ __launch_bounds__(256) void k_pool(const u16* __restrict__ inA,
                                              const int* __restrict__ rp,
                                              const int* __restrict__ sl,
                                              const float* __restrict__ uN,
                                              float* __restrict__ GlOut,
                                              u16* __restrict__ outA, int nseg) {
  int wid = blockIdx.x * 4 + ((int)threadIdx.x >> 6);
  int lane = threadIdx.x & 63;
  if (wid >= nseg) return;
  int a = rp[wid], b = rp[wid + 1];
  const int c0 = lane, c1 = lane + 64, c2 = lane + 128;
  const bool h2v = c2 < CC;
  float acc0 = 0.f, acc1 = 0.f, acc2 = 0.f;
  for (int s = a; s < b; ++s) {
    size_t off = (size_t)sl[s] * HALF;
    acc0 += h2f(inA[off + c0]);
    acc1 += h2f(inA[off + c1]);
    if (h2v) acc2 += h2f(inA[off + c2]);
  }
  int cnt = b - a;
  float inv = 1.f / (float)(cnt > 1 ? cnt : 1);
  float v0 = acc0 * inv, v1 = acc1 * inv, v2 = acc2 * inv;
  u16* oa = outA + (size_t)wid * HALF;
  oa[c0] = f2h(v0);
  oa[c1] = f2h(v1);
  if (h2v) oa[c2] = f2h(v2);
  else if (c2 < HALF) oa[c2] = 0;
  if (uN) {
    float4 ua = *(const float4*)(uN + c0 * 4);
    float4 ub = *(const float4*)(uN + c1 * 4);
    float lx = v0 * ua.x + v1 * ub.x;
    float ly = v0 * ua.y + v1 * ub.y;
    float lz = v0 * ua.z + v1 * ub.z;
    float lw = v0 * ua.w + v1 * ub.w;
    if (h2v) {
      float4 uc_ = *(const float4*)(uN + c2 * 4);
      lx += v2 * uc_.x; ly += v2 * uc_.y; lz += v2 * uc_.z; lw += v2 * uc_.w;
    }
#pragma unroll
    for (int off = 32; off > 0; off >>= 1) {
      lx += __shfl_xor(lx, off);
      ly += __shfl_xor(ly, off);
      lz += __shfl_xor(lz, off);
      lw += __shfl_xor(lw, off);
    }
    if (lane == 0) {
      float* gl = GlOut + (size_t)wid * 4;
      gl[0] = lx; gl[1] = ly; gl[2] = lz; gl[3] = lw;
    }
  }
}

// ============================ host ============================
extern "C" void kernel_launch(void* const* d_in, const int* in_sizes, int n_in,
                              void* d_out, int out_size, void* d_ws, size_t ws_size,
                              hipStream_t stream) {
  (void)n_in; (void)out_size;
  const float* x    = (const float*)d_in[0];
  const int*   e0   = (const int*)d_in[1];
  const int*   e1   = (const int*)d_in[2];
  const int*   e2   = (const int*)d_in[3];
  const int*   cl1  = (const int*)d_in[4];
  const int*   cl2  = (const int*)d_in[5];
  const float* W01  = (const float*)d_in[9];
  const float* u01  = (const float*)d_in[10];
  const float* c01  = (const float*)d_in[11];
  const float* b01  = (const float*)d_in[12];
  const float* sW01 = (const float*)d_in[13];
  const float* sb01 = (const float*)d_in[14];
  const float* g01  = (const float*)d_in[15];
  const float* be01 = (const float*)d_in[16];
  const float* Ws   = (const float*)d_in[17];
  const float* us   = (const float*)d_in[18];
  const float* cs   = (const float*)d_in[19];
  const float* bs   = (const float*)d_in[20];
  const float* gs   = (const float*)d_in[21];
  const float* bes  = (const float*)d_in[22];
  const float* Wc   = (const float*)d_in[23];
  const float* uc   = (const float*)d_in[24];
  const float* cc   = (const float*)d_in[25];
  const float* bc   = (const float*)d_in[26];
  const float* sWc  = (const float*)d_in[27];
  const float* sbc  = (const float*)d_in[28];
  const float* gc   = (const float*)d_in[29];
  const float* bec  = (const float*)d_in[30];
  const float* Wo   = (const float*)d_in[31];
  const float* uo   = (const float*)d_in[32];
  const float* co   = (const float*)d_in[33];
  const float* bo   = (const float*)d_in[34];
  const float* sWo  = (const float*)d_in[35];
  const float* sbo  = (const float*)d_in[36];

  const int N0 = in_sizes[0] / 4;
  const int nE0 = in_sizes[1] / 2;
  const int nE1 = in_sizes[2] / 2;
  const int nE2 = in_sizes[3] / 2;
  const int N1 = 5000, N2 = 1250;

  // ---- workspace layout ----
  float* fp = (float*)d_ws;
  auto alloc_f = [&](size_t n) { n = (n + 15) & ~(size_t)15; float* p = fp; fp += n; return p; };
  auto alloc_h = [&](size_t n) { return (u16*)alloc_f((n + 1) / 2); };
  u16*   Gy = alloc_h((size_t)N0 * 8);
  float* Gl = alloc_f((size_t)N0 * 4);
  float* Gs = alloc_f((size_t)N0 * CC);
  float* Gw = alloc_f((size_t)N0 * HALF);
  float* invd = alloc_f((size_t)N0);
  u16* zA = alloc_h((size_t)N0 * 576);
  u16* zB = alloc_h((size_t)N0 * 576);
  u16* a0A = alloc_h((size_t)N0 * HALF);
  u16* a0B = alloc_h((size_t)N0 * HALF);
  u16* a1A = alloc_h((size_t)N1 * HALF);
  u16* a1B = alloc_h((size_t)N1 * HALF);
  u16* a2A = alloc_h((size_t)N2 * HALF);
  u16* a2B = alloc_h((size_t)N2 * HALF);
  u16* xb  = alloc_h((size_t)N0 * 32);
  u16* B01  = alloc_h(S01);
  u16* Bc2  = alloc_h((size_t)2 * SC);
  u16* Bpo  = alloc_h(SO);
  u16* Q01  = alloc_h(T01);
  u16* Qs10 = alloc_h((size_t)10 * TS);
  u16* Qc2  = alloc_h((size_t)2 * TC);
  u16* Qpad = alloc_h((size_t)64 * 1152);  // OOB-read pad for col-blocks past M
  (void)Qpad;
  int* ipb = (int*)fp;
  auto alloc_i = [&](size_t n) { int* p = ipb; ipb += n; return p; };
  int* rp0  = alloc_i(N0 + 1);
  int* sl0  = alloc_i(nE0);
  int* rp1  = alloc_i(N1 + 1);
  int* sl1  = alloc_i(nE1);
  int* rp2  = alloc_i(N2 + 1);
  int* sl2  = alloc_i(nE2);
  int* rpc1 = alloc_i(N1 + 1);
  int* slc1 = alloc_i(N0);
  int* rpc2 = alloc_i(N2 + 1);
  int* slc2 = alloc_i(N1);
  int* cur0 = alloc_i(N0);
  int* cur1 = alloc_i(N1);
  int* cur2 = alloc_i(N2);
  int* cur3 = alloc_i(N1);
  int* cur4 = alloc_i(N2);
  const int curTot = N0 + N1 + N2 + N1 + N2;
  if ((size_t)((char*)ipb - (char*)d_ws) > ws_size) return;

  auto cdiv = [](int a, int b) { return (a + b - 1) / b; };

  // ---- CSR build ----
  k_zero_i32<<<cdiv(curTot, 256), 256, 0, stream>>>(cur0, curTot);
  {
    int tot = nE0 + nE1 + nE2 + N0 + N1;
    k_hist_all<<<cdiv(tot, 256), 256, 0, stream>>>(e0, nE0, e1, nE1, e2, nE2, cl1, N0, cl2, N1,
                                                   cur0, cur1, cur2, cur3, cur4);
    k_exscan5<<<5, 1024, 0, stream>>>(cur0, N0, rp0, cur1, N1, rp1, cur2, N2, rp2,
                                      cur3, N1, rpc1, cur4, N2, rpc2);
    k_scatter_all<<<cdiv(tot, 256), 256, 0, stream>>>(e0, nE0, e1, nE1, e2, nE2, cl1, N0, cl2, N1,
                                                      cur0, cur1, cur2, cur3, cur4,
                                                      sl0, sl1, sl2, slc1, slc2);
  }
  // ---- weight packs ----
  {
    int tot1 = S01 + 2 * SC + SO + N0 * 32;
    k_pack1<<<cdiv(tot1, 256), 256, 0, stream>>>(u01, sW01, uc, sWc, Wo, uo, sWo, x,
                                                 B01, Bc2, Bpo, xb, N0);
    int tot2 = T01 + 10 * TS + 2 * TC;
    k_pack2<<<cdiv(tot2, 256), 256, 0, stream>>>(W01, Ws, Wc, Q01, Qs10, Qc2);
  }

  auto ci  = [&](int i) { return cs + (size_t)i * HH; };
  auto bi  = [&](int i) { return bs + (size_t)i * CC; };
  auto gi  = [&](int i) { return gs + (size_t)i * CC; };
  auto bei = [&](int i) { return bes + (size_t)i * CC; };
  auto usL = [&](int i) { return us + (size_t)i * CC * HH; };

  // identity conv: aggz + GEMM2 + post (Gl pre-computed by prior post/pool)
  auto conv_plain = [&](const u16* aIn, const u16* Bq, int n,
                        const int* rp, const int* sl, const float* cv,
                        const float* bp, const float* gp, const float* bep,
                        const float* uNext, u16* aOut) {
    k_aggz<<<cdiv(n, 4), 256, 0, stream>>>(aIn, HALF, 140, nullptr, Gl, cv, rp, sl,
                                           zA, 576, 144, invd, n);
    dim3 g2(3, cdiv(n, 128));
    k_gemm_mfma<<<g2, 256, 0, stream>>>(zA, nullptr, nullptr, Bq, Gy, Gl, Gw,
                                        -4, 160, n, 576, 576, HALF, HALF);
    k_post<<<cdiv(n, 4), 256, 0, stream>>>(Gw, invd, bp, gp, bep, aIn, nullptr, nullptr,
                                           uNext, Gl, aOut, n);
  };

  // ---- conv01 ----
  {
    dim3 g1(3, cdiv(N0, 128));
    k_gemm_mfma<<<g1, 256, 0, stream>>>(xb, nullptr, nullptr, B01, Gy, Gl, Gs,
                                        0, 140, N0, 32, 32, HALF, HALF);
    k_aggz<<<cdiv(N0, 4), 256, 0, stream>>>(xb, 32, 4, nullptr, Gl, c01, rp0, sl0,
                                            zA, 32, 8, invd, N0);
    dim3 g2(3, cdiv(N0, 128));
    k_gemm_mfma<<<g2, 256, 0, stream>>>(zA, nullptr, nullptr, Q01, Gy, Gl, Gw,
                                        -4, 160, N0, 32, 32, HALF, HALF);
    k_post<<<cdiv(N0, 4), 256, 0, stream>>>(Gw, invd, b01, g01, be01, nullptr, Gs, sb01,
                                            usL(0), Gl, a0A, N0);
  }
  // conv02 -> copy0 = a0B (no next-identity logits; pool1 computes them)
  conv_plain(a0A, Qs10 + (size_t)0 * TS, N0, rp0, sl0, ci(0), bi(0), gi(0), bei(0),
             nullptr, a0B);
  // pool1 (computes Gl for conv11)
  k_pool<<<cdiv(N1, 4), 256, 0, stream>>>(a0B, rpc1, slc1, usL(1), Gl, a1A, N1);
  // conv11 (post computes Gl for conv12), conv12 (no logits; conv13 has own gemm1)
  conv_plain(a1A, Qs10 + (size_t)1 * TS, N1, rp1, sl1, ci(1), bi(1), gi(1), bei(1),
             usL(2), a1B);
  conv_plain(a1B, Qs10 + (size_t)2 * TS, N1, rp1, sl1, ci(2), bi(2), gi(2), bei(2),
             nullptr, a1A);
  // pool2 (computes Gl for conv21)
  k_pool<<<cdiv(N2, 4), 256, 0, stream>>>(a1A, rpc2, slc2, usL(3), Gl, a2A, N2);
  // conv21 (Gl for conv22), conv22 (none)
  conv_plain(a2A, Qs10 + (size_t)3 * TS, N2, rp2, sl2, ci(3), bi(3), gi(3), bei(3),
             usL(4), a2B);
  conv_plain(a2B, Qs10 + (size_t)4 * TS, N2, rp2, sl2, ci(4), bi(4), gi(4), bei(4),
             nullptr, a2A);
  // ---- conv13: concat [unpool2(a2A) | a1A] ----
  {
    dim3 g1(3, cdiv(N1, 128));
    k_gemm_mfma<<<g1, 256, 0, stream>>>(a2A, a1A, cl2, Bc2 + 0 * SC, Gy, Gl, Gs,
                                        0, 140, N1, 320, HALF, HALF, HALF);
    k_aggz<<<cdiv(N1, 4), 256, 0, stream>>>(a2A, HALF, 140, cl2, Gl, cc, rp1, sl1,
                                            zA, 576, 144, invd, N1);
    k_aggz<<<cdiv(N1, 4), 256, 0, stream>>>(a1A, HALF, 140, nullptr, Gl, cc, rp1, sl1,
                                            zB, 576, 144, invd, N1);
    dim3 g2(3, cdiv(N1, 128));
    k_gemm_mfma<<<g2, 256, 0, stream>>>(zA, zB, nullptr, Qc2 + (size_t)0 * TC, Gy, Gl, Gw,
                                        -4, 160, N1, 1152, 576, 576, 576);
    k_post<<<cdiv(N1, 4), 256, 0, stream>>>(Gw, invd, bc, gc, bec, nullptr, Gs, sbc,
                                            usL(5), Gl, a1B, N1);
  }
  // conv14 (Gl for conv15), conv15 (Gl for conv16), conv16 (none)
  conv_plain(a1B, Qs10 + (size_t)5 * TS, N1, rp1, sl1, ci(5), bi(5), gi(5), bei(5),
             usL(6), a1A);
  conv_plain(a1A, Qs10 + (size_t)6 * TS, N1, rp1, sl1, ci(6), bi(6), gi(6), bei(6),
             usL(7), a1B);
  conv_plain(a1B, Qs10 + (size_t)7 * TS, N1, rp1, sl1, ci(7), bi(7), gi(7), bei(7),
             nullptr, a1A);
  // ---- conv03: concat [unpool1(a1A) | a0B] ----
  {
    dim3 g1(3, cdiv(N0, 128));
    k_gemm_mfma<<<g1, 256, 0, stream>>>(a1A, a0B, cl1, Bc2 + 1 * SC, Gy, Gl, Gs,
                                        0, 140, N0, 320, HALF, HALF, HALF);
    k_aggz<<<cdiv(N0, 4), 256, 0, stream>>>(a1A, HALF, 140, cl1, Gl, cc + HH, rp0, sl0,
                                            zA, 576, 144, invd, N0);
    k_aggz<<<cdiv(N0, 4), 256, 0, stream>>>(a0B, HALF, 140, nullptr, Gl, cc + HH, rp0, sl0,
                                            zB, 576, 144, invd, N0);
    dim3 g2(3, cdiv(N0, 128));
    k_gemm_mfma<<<g2, 256, 0, stream>>>(zA, zB, nullptr, Qc2 + (size_t)1 * TC, Gy, Gl, Gw,
                                        -4, 160, N0, 1152, 576, 576, 576);
    k_post<<<cdiv(N0, 4), 256, 0, stream>>>(Gw, invd, bc + CC, gc + CC, bec + CC, nullptr,
                                            Gs, sbc + CC, usL(8), Gl, a0A, N0);
  }
  // conv04 (Gl for conv05), conv05 (none; conv06 has own gemm1)
  conv_plain(a0A, Qs10 + (size_t)8 * TS, N0, rp0, sl0, ci(8), bi(8), gi(8), bei(8),
             usL(9), a0B);
  conv_plain(a0B, Qs10 + (size_t)9 * TS, N0, rp0, sl0, ci(9), bi(9), gi(9), bei(9),
             nullptr, a0A);
  // ---- conv06 ----
  {
    dim3 g1(1, cdiv(N0, 128));
    k_gemm_mfma<<<g1, 256, 0, stream>>>(a0A, nullptr, nullptr, Bpo, Gy, Gl, Gs,
                                        4, 1, N0, 160, HALF, HALF, HALF);
    k_out<<<cdiv(N0, 4), 256, 0, stream>>>(Gy, Gl, co, bo, Gs, sbo, rp0, sl0, (float*)d_out, N0);
  }
}

// Round 12
// 670.204 us; speedup vs baseline: 2.0579x; 1.2658x over previous
//
#include <hip/hip_runtime.h>
#include <math.h>

#define HH 4
#define CC 140
#define HALF 160   // padded K of one concat half / one plain input

typedef __attribute__((ext_vector_type(8))) short short8;
typedef __attribute__((ext_vector_type(8))) _Float16 half8;
typedef __attribute__((ext_vector_type(4))) float f32x4;
typedef __attribute__((ext_vector_type(2))) _Float16 h2;
typedef unsigned short u16;

__device__ inline u16 f2h(float x) {
  union { _Float16 h; u16 u; } v; v.h = (_Float16)x; return v.u;
}
__device__ inline float h2f(u16 u) {
  union { _Float16 h; u16 u; } v; v.u = u; return (float)v.h;
}
__device__ inline h2 u2h2(unsigned u) {
  union { unsigned u; h2 h; } v; v.u = u; return v.h;
}
__device__ inline float dot2(h2 a, h2 b, float c) {
#if __has_builtin(__builtin_amdgcn_fdot2)
  return __builtin_amdgcn_fdot2(a, b, c, false);
#else
  return c + (float)a[0] * (float)b[0] + (float)a[1] * (float)b[1];
#endif
}

// ============================ fused CSR build (4 launches) ============================
__global__ __launch_bounds__(256) void k_zero_i32(int* __restrict__ p, int n) {
  int i = blockIdx.x * 256 + threadIdx.x;
  if (i < n) p[i] = 0;
}
__global__ __launch_bounds__(256) void k_hist_all(
    const int* __restrict__ e0, int nE0, const int* __restrict__ e1, int nE1,
    const int* __restrict__ e2, int nE2, const int* __restrict__ cl1, int n0,
    const int* __restrict__ cl2, int n1,
    int* __restrict__ c0, int* __restrict__ c1, int* __restrict__ c2,
    int* __restrict__ c3, int* __restrict__ c4) {
  int j = blockIdx.x * 256 + threadIdx.x;
  if (j < nE0) { atomicAdd(&c0[e0[nE0 + j]], 1); return; }
  j -= nE0;
  if (j < nE1) { atomicAdd(&c1[e1[nE1 + j]], 1); return; }
  j -= nE1;
  if (j < nE2) { atomicAdd(&c2[e2[nE2 + j]], 1); return; }
  j -= nE2;
  if (j < n0) { atomicAdd(&c3[cl1[j]], 1); return; }
  j -= n0;
  if (j < n1) { atomicAdd(&c4[cl2[j]], 1); }
}
__global__ __launch_bounds__(1024) void k_exscan5(
    int* __restrict__ c0, int n0, int* __restrict__ r0,
    int* __restrict__ c1, int n1, int* __restrict__ r1,
    int* __restrict__ c2, int n2, int* __restrict__ r2,
    int* __restrict__ c3, int n3, int* __restrict__ r3,
    int* __restrict__ c4, int n4, int* __restrict__ r4) {
  int* in; int n; int* out;
  switch (blockIdx.x) {
    case 0: in = c0; n = n0; out = r0; break;
    case 1: in = c1; n = n1; out = r1; break;
    case 2: in = c2; n = n2; out = r2; break;
    case 3: in = c3; n = n3; out = r3; break;
    default: in = c4; n = n4; out = r4; break;
  }
  __shared__ int buf[1024];
  __shared__ int carry_s;
  if (threadIdx.x == 0) carry_s = 0;
  __syncthreads();
  for (int base = 0; base < n; base += 1024) {
    int i = base + (int)threadIdx.x;
    int v = (i < n) ? in[i] : 0;
    buf[threadIdx.x] = v;
    __syncthreads();
    int x = v;
    for (int off = 1; off < 1024; off <<= 1) {
      int t = (threadIdx.x >= (unsigned)off) ? buf[threadIdx.x - off] : 0;
      __syncthreads();
      x += t;
      buf[threadIdx.x] = x;
      __syncthreads();
    }
    int carry = carry_s;
    if (i < n) {
      int pref = carry + x - v;
      out[i] = pref;
      in[i] = pref;
    }
    __syncthreads();
    if (threadIdx.x == 1023) carry_s = carry + buf[1023];
    __syncthreads();
  }
  if (threadIdx.x == 0) out[n] = carry_s;
}
__global__ __launch_bounds__(256) void k_scatter_all(
    const int* __restrict__ e0, int nE0, const int* __restrict__ e1, int nE1,
    const int* __restrict__ e2, int nE2, const int* __restrict__ cl1, int n0,
    const int* __restrict__ cl2, int n1,
    int* __restrict__ c0, int* __restrict__ c1, int* __restrict__ c2,
    int* __restrict__ c3, int* __restrict__ c4,
    int* __restrict__ s0, int* __restrict__ s1, int* __restrict__ s2,
    int* __restrict__ s3, int* __restrict__ s4) {
  int j = blockIdx.x * 256 + threadIdx.x;
  if (j < nE0) { int p = atomicAdd(&c0[e0[nE0 + j]], 1); s0[p] = e0[j]; return; }
  j -= nE0;
  if (j < nE1) { int p = atomicAdd(&c1[e1[nE1 + j]], 1); s1[p] = e1[j]; return; }
  j -= nE1;
  if (j < nE2) { int p = atomicAdd(&c2[e2[nE2 + j]], 1); s2[p] = e2[j]; return; }
  j -= nE2;
  if (j < n0) { int p = atomicAdd(&c3[cl1[j]], 1); s3[p] = j; return; }
  j -= n0;
  if (j < n1) { int p = atomicAdd(&c4[cl2[j]], 1); s4[p] = j; }
}

// ============================ mega weight pack (f16 single plane) ============================
__device__ inline void pack_one(int idx, const float* __restrict__ W,
                                const float* __restrict__ u, const float* __restrict__ sW,
                                u16* __restrict__ out, int C, int K1, int K2, int Kpad) {
  int col = idx / Kpad, kp = idx - col * Kpad;
  int ksrc = -1;
  if (kp < K1) ksrc = kp;
  else if (kp >= HALF && kp - HALF < K2) ksrc = K1 + (kp - HALF);
  float v = 0.f;
  if (ksrc >= 0) {
    if (col < 4 * C) {
      int c = col >> 2, h = col & 3;
      v = W[(size_t)ksrc * 4 * C + h * C + c];
    } else if (col < 4 * C + 4) {
      v = u[(size_t)ksrc * 4 + (col - 4 * C)];
    } else if (sW && col < 5 * C + 4) {
      v = sW[(size_t)ksrc * C + (col - 4 * C - 4)];
    }
  }
  out[idx] = f2h(v);
}
#define P01 (704 * 32)
#define PCAT (704 * 320)
#define PO (64 * 160)
#define PS (576 * 160)
__global__ __launch_bounds__(256) void k_pack_all(
    const float* __restrict__ W01, const float* __restrict__ u01, const float* __restrict__ sW01,
    const float* __restrict__ Wc, const float* __restrict__ uc, const float* __restrict__ sWc,
    const float* __restrict__ Wo, const float* __restrict__ uo, const float* __restrict__ sWo,
    const float* __restrict__ Ws, const float* __restrict__ us,
    const float* __restrict__ x,
    u16* __restrict__ Bp01, u16* __restrict__ Bpc0, u16* __restrict__ Bpc1,
    u16* __restrict__ Bpo, u16* __restrict__ Bps_all, u16* __restrict__ xb, int N0) {
  int j = blockIdx.x * 256 + threadIdx.x;
  if (j < P01) { pack_one(j, W01, u01, sW01, Bp01, CC, 4, 0, 32); return; }
  j -= P01;
  if (j < PCAT) { pack_one(j, Wc, uc, sWc, Bpc0, CC, CC, CC, 320); return; }
  j -= PCAT;
  if (j < PCAT) {
    pack_one(j, Wc + (size_t)2 * CC * HH * CC, uc + (size_t)2 * CC * HH,
             sWc + (size_t)2 * CC * CC, Bpc1, CC, CC, CC, 320);
    return;
  }
  j -= PCAT;
  if (j < PO) { pack_one(j, Wo, uo, sWo, Bpo, 1, CC, 0, 160); return; }
  j -= PO;
  if (j < 10 * PS) {
    int layer = j / PS, r = j - layer * PS;
    pack_one(r, Ws + (size_t)layer * CC * 4 * CC, us + (size_t)layer * CC * 4, nullptr,
             Bps_all + (size_t)layer * PS, CC, CC, 0, 160);
    return;
  }
  j -= 10 * PS;
  if (j < N0 * 32) {
    int i = j >> 5, c = j & 31;
    xb[j] = f2h(c < 4 ? x[(size_t)i * 4 + c] : 0.f);
  }
}

// ============================ f16 MFMA GEMM (single pass), split output ============================
__global__ __launch_bounds__(256) void k_gemm_mfma(
    const u16* __restrict__ A1, const u16* __restrict__ A2,
    const int* __restrict__ amap, const u16* __restrict__ Bp,
    u16* __restrict__ Gy, float* __restrict__ Gl, float* __restrict__ Gs,
    int yEnd, int Cs, int N, int Kpad, int lda1) {
  __shared__ __align__(16) u16 As[128 * 32];
  __shared__ __align__(16) u16 Bs[64 * 32];
  const int tid = threadIdx.x;
  const int row0 = blockIdx.y * 128, col0 = blockIdx.x * 64;
  const int w = tid >> 6, lane = tid & 63;
  const int wm = w >> 1, wn = w & 1;
  const int arow = lane & 15, chunk = lane >> 4;
  const int swz = chunk ^ (arow & 3);
  f32x4 acc[4][2];
#pragma unroll
  for (int i = 0; i < 4; ++i)
#pragma unroll
    for (int j = 0; j < 2; ++j) acc[i][j] = (f32x4){0.f, 0.f, 0.f, 0.f};
  const int sar = tid >> 1;
  const int sak = (tid & 1) * 16;
  const int sbc = tid >> 2;
  const int sbk = (tid & 3) * 8;
  for (int k0 = 0; k0 < Kpad; k0 += 32) {
    {
      int gr = row0 + sar;
      short8 v0 = {0, 0, 0, 0, 0, 0, 0, 0}, v1 = v0;
      if (gr < N) {
        int kp0 = k0 + sak;
        const u16* b_;
        int rr, kk, ld;
        if (A2 && kp0 >= HALF) {
          b_ = A2; rr = gr; kk = kp0 - HALF; ld = HALF;
        } else {
          b_ = A1; rr = amap ? amap[gr] : gr; kk = kp0; ld = lda1;
        }
        const u16* p = b_ + (size_t)rr * ld + kk;
        v0 = *(const short8*)(p);
        v1 = *(const short8*)(p + 8);
      }
      int c0 = sak >> 3, sw = sar & 3;
      *(short8*)(As + sar * 32 + ((c0 ^ sw) << 3)) = v0;
      *(short8*)(As + sar * 32 + (((c0 + 1) ^ sw) << 3)) = v1;
    }
    {
      int gc = col0 + sbc;
      short8 v = *(const short8*)(Bp + (size_t)gc * Kpad + k0 + sbk);
      int c = sbk >> 3, sw = sbc & 3;
      *(short8*)(Bs + sbc * 32 + ((c ^ sw) << 3)) = v;
    }
    __syncthreads();
    half8 bf[2], af[4];
#pragma unroll
    for (int ni = 0; ni < 2; ++ni) {
      int col = wn * 32 + ni * 16 + arow;
      bf[ni] = *(const half8*)(Bs + col * 32 + (swz << 3));
    }
#pragma unroll
    for (int mi = 0; mi < 4; ++mi) {
      int r = wm * 64 + mi * 16 + arow;
      af[mi] = *(const half8*)(As + r * 32 + (swz << 3));
    }
#pragma unroll
    for (int mi = 0; mi < 4; ++mi)
#pragma unroll
      for (int ni = 0; ni < 2; ++ni)
        acc[mi][ni] = __builtin_amdgcn_mfma_f32_16x16x32_f16(af[mi], bf[ni], acc[mi][ni], 0, 0, 0);
    __syncthreads();
  }
  const int crow = (lane >> 4) * 4, ccol = lane & 15;
#pragma unroll
  for (int mi = 0; mi < 4; ++mi) {
    int gr0 = row0 + wm * 64 + mi * 16 + crow;
#pragma unroll
    for (int ni = 0; ni < 2; ++ni) {
      int gc = col0 + wn * 32 + ni * 16 + ccol;
#pragma unroll
      for (int j = 0; j < 4; ++j) {
        int gr = gr0 + j;
        if (gr >= N) continue;
        float v = acc[mi][ni][j];
        if (gc < yEnd) Gy[(size_t)gr * yEnd + gc] = f2h(v);
        else if (gc < yEnd + 4) Gl[(size_t)gr * 4 + (gc - yEnd)] = v;
        else if (gc < yEnd + 4 + Cs) Gs[(size_t)gr * Cs + (gc - yEnd - 4)] = v;
      }
    }
  }
}

// ============================ fused FeaSt agg + LN + skip + relu ============================
// Gy f16 (n,560) head-minor; Gl f32 (n,4); distributed softmax; batched (MLP=24) gather + fdot2
__global__ __launch_bounds__(256) void k_agg(
    const u16* __restrict__ Gy, const float* __restrict__ Gl,
    const float* __restrict__ cv, const float* __restrict__ bias,
    const float* __restrict__ g, const float* __restrict__ be,
    const u16* __restrict__ skipA,
    const float* __restrict__ Gs, const float* __restrict__ sb,
    const int* __restrict__ rp, const int* __restrict__ sl,
    u16* __restrict__ outA, int n, int relu) {
  int wid = blockIdx.x * 4 + ((int)threadIdx.x >> 6);
  int lane = threadIdx.x & 63;
  if (wid >= n) return;
  float4 la = *(const float4*)(Gl + (size_t)wid * 4);
  float d0 = cv[0] - la.x, d1 = cv[1] - la.y;
  float d2 = cv[2] - la.z, d3 = cv[3] - la.w;
  int eb = rp[wid], ee = rp[wid + 1];
  const int c0 = lane, c1 = lane + 64, c2 = lane + 128;
  const bool h2v = c2 < CC;
  float acc0 = 0.f, acc1 = 0.f, acc2 = 0.f;
  for (int base = eb; base < ee; base += 64) {
    int m = min(ee - base, 64);
    // phase 1: lane j computes softmax weights for edge base+j
    int sreg = 0;
    int q01 = 0, q23 = 0;
    if (lane < m) {
      sreg = sl[base + lane];
      float4 lg = *(const float4*)(Gl + (size_t)sreg * 4);
      float t0 = lg.x + d0, t1 = lg.y + d1, t2 = lg.z + d2, t3 = lg.w + d3;
      float mx = fmaxf(fmaxf(t0, t1), fmaxf(t2, t3));
      float q0 = __expf(t0 - mx), q1 = __expf(t1 - mx);
      float q2 = __expf(t2 - mx), q3 = __expf(t3 - mx);
      float qi = 1.f / (q0 + q1 + q2 + q3);
      q01 = (int)((unsigned)f2h(q0 * qi) | ((unsigned)f2h(q1 * qi) << 16));
      q23 = (int)((unsigned)f2h(q2 * qi) | ((unsigned)f2h(q3 * qi) << 16));
    }
    // phase 2: batches of 8 edges — issue all 24 gathers, then 48 dots
    for (int jb = 0; jb < m; jb += 8) {
      uint2 Y0[8], Y1[8], Y2[8];
      unsigned P01v[8], P23v[8];
#pragma unroll
      for (int t = 0; t < 8; ++t) {
        int j = jb + t;  // <= 63 always
        int s = __shfl(sreg, j);
        unsigned p01 = (unsigned)__shfl(q01, j);
        unsigned p23 = (unsigned)__shfl(q23, j);
        bool v = (j < m);
        P01v[t] = v ? p01 : 0u;
        P23v[t] = v ? p23 : 0u;
        if (v) {
          const u16* gy = Gy + (size_t)s * 560;
          Y0[t] = *(const uint2*)(gy + (c0 << 2));
          Y1[t] = *(const uint2*)(gy + (c1 << 2));
          Y2[t] = h2v ? *(const uint2*)(gy + (c2 << 2)) : make_uint2(0u, 0u);
        } else {
          Y0[t] = make_uint2(0u, 0u);
          Y1[t] = make_uint2(0u, 0u);
          Y2[t] = make_uint2(0u, 0u);
        }
      }
#pragma unroll
      for (int t = 0; t < 8; ++t) {
        h2 p01 = u2h2(P01v[t]), p23 = u2h2(P23v[t]);
        acc0 = dot2(u2h2(Y0[t].x), p01, acc0);
        acc0 = dot2(u2h2(Y0[t].y), p23, acc0);
        acc1 = dot2(u2h2(Y1[t].x), p01, acc1);
        acc1 = dot2(u2h2(Y1[t].y), p23, acc1);
        acc2 = dot2(u2h2(Y2[t].x), p01, acc2);
        acc2 = dot2(u2h2(Y2[t].y), p23, acc2);
      }
    }
  }
  int cnt = ee - eb;
  float inv = 1.f / (float)(cnt > 1 ? cnt : 1);
  float v0 = acc0 * inv + bias[c0];
  float v1 = acc1 * inv + bias[c1];
  float v2 = h2v ? acc2 * inv + bias[c2] : 0.f;
  if (g) {
    float s1 = v0 + v1 + v2;
    float s2 = v0 * v0 + v1 * v1 + v2 * v2;
#pragma unroll
    for (int off = 32; off > 0; off >>= 1) {
      s1 += __shfl_xor(s1, off);
      s2 += __shfl_xor(s2, off);
    }
    float mu = s1 * (1.0f / CC);
    float var = s2 * (1.0f / CC) - mu * mu;
    float r = rsqrtf(var + 1e-5f);
    v0 = (v0 - mu) * r * g[c0] + be[c0];
    v1 = (v1 - mu) * r * g[c1] + be[c1];
    if (h2v) v2 = (v2 - mu) * r * g[c2] + be[c2];
  }
  if (skipA) {
    const u16* sk = skipA + (size_t)wid * HALF;
    v0 += h2f(sk[c0]);
    v1 += h2f(sk[c1]);
    if (h2v) v2 += h2f(sk[c2]);
  } else {
    const float* gsr = Gs + (size_t)wid * CC;
    v0 += gsr[c0] + sb[c0];
    v1 += gsr[c1] + sb[c1];
    if (h2v) v2 += gsr[c2] + sb[c2];
  }
  if (relu) {
    v0 = fmaxf(v0, 0.f); v1 = fmaxf(v1, 0.f); v2 = fmaxf(v2, 0.f);
  }
  u16* oa = outA + (size_t)wid * HALF;
  oa[c0] = f2h(v0);
  oa[c1] = f2h(v1);
  if (h2v) oa[c2] = f2h(v2);
  else if (c2 < HALF) oa[c2] = 0;
}

// conv06
__global__ __launch_bounds__(256) void k_out(
    const u16* __restrict__ Gy, const float* __restrict__ Gl,
    const float* __restrict__ cv, const float* __restrict__ bo,
    const float* __restrict__ Gs, const float* __restrict__ sbo,
    const int* __restrict__ rp, const int* __restrict__ sl,
    float* __restrict__ out, int n) {
  int wid = blockIdx.x * 4 + ((int)threadIdx.x >> 6);
  int lane = threadIdx.x & 63;
  if (wid >= n) return;
  float4 la = *(const float4*)(Gl + (size_t)wid * 4);
  float d0 = cv[0] - la.x, d1 = cv[1] - la.y;
  float d2 = cv[2] - la.z, d3 = cv[3] - la.w;
  int eb = rp[wid], ee = rp[wid + 1];
  float part = 0.f;
  for (int e = eb + lane; e < ee; e += 64) {
    int s = sl[e];
    float4 lg = *(const float4*)(Gl + (size_t)s * 4);
    float t0 = lg.x + d0, t1 = lg.y + d1, t2 = lg.z + d2, t3 = lg.w + d3;
    float m = fmaxf(fmaxf(t0, t1), fmaxf(t2, t3));
    float q0 = __expf(t0 - m), q1 = __expf(t1 - m), q2 = __expf(t2 - m), q3 = __expf(t3 - m);
    float qi = 1.f / (q0 + q1 + q2 + q3);
    uint2 y = *(const uint2*)(Gy + (size_t)s * 4);
    h2 y01 = u2h2(y.x), y23 = u2h2(y.y);
    part += (q0 * (float)y01[0] + q1 * (float)y01[1] +
             q2 * (float)y23[0] + q3 * (float)y23[1]) * qi;
  }
#pragma unroll
  for (int off = 32; off > 0; off >>= 1) part += __shfl_xor(part, off);
  if (lane == 0) {
    int cnt = ee - eb;
    out[wid] = part / (float)(cnt > 1 ? cnt : 1) + bo[0] + Gs[wid] + sbo[0];
  }
}

// ============================ pool (f16 in/out) ============================
__global__ __launch_bounds__(256) void k_pool(const u16* __restrict__ inA,
                                              const int* __restrict__ rp,
                                              const int* __restrict__ sl,
                                              u16* __restrict__ outA, int nseg) {
  int wid = blockIdx.x * 4 + ((int)threadIdx.x >> 6);
  int lane = threadIdx.x & 63;
  if (wid >= nseg) return;
  int a = rp[wid], b = rp[wid + 1];
  const int c0 = lane, c1 = lane + 64, c2 = lane + 128;
  const bool h2v = c2 < CC;
  float acc0 = 0.f, acc1 = 0.f, acc2 = 0.f;
  for (int s = a; s < b; ++s) {
    size_t off = (size_t)sl[s] * HALF;
    acc0 += h2f(inA[off + c0]);
    acc1 += h2f(inA[off + c1]);
    if (h2v) acc2 += h2f(inA[off + c2]);
  }
  int cnt = b - a;
  float inv = 1.f / (float)(cnt > 1 ? cnt : 1);
  u16* oa = outA + (size_t)wid * HALF;
  oa[c0] = f2h(acc0 * inv);
  oa[c1] = f2h(acc1 * inv);
  if (h2v) oa[c2] = f2h(acc2 * inv);
  else if (c2 < HALF) oa[c2] = 0;
}

// ============================ host ============================
extern "C" void kernel_launch(void* const* d_in, const int* in_sizes, int n_in,
                              void* d_out, int out_size, void* d_ws, size_t ws_size,
                              hipStream_t stream) {
  (void)n_in; (void)out_size;
  const float* x    = (const float*)d_in[0];
  const int*   e0   = (const int*)d_in[1];
  const int*   e1   = (const int*)d_in[2];
  const int*   e2   = (const int*)d_in[3];
  const int*   cl1  = (const int*)d_in[4];
  const int*   cl2  = (const int*)d_in[5];
  const float* W01  = (const float*)d_in[9];
  const float* u01  = (const float*)d_in[10];
  const float* c01  = (const float*)d_in[11];
  const float* b01  = (const float*)d_in[12];
  const float* sW01 = (const float*)d_in[13];
  const float* sb01 = (const float*)d_in[14];
  const float* g01  = (const float*)d_in[15];
  const float* be01 = (const float*)d_in[16];
  const float* Ws   = (const float*)d_in[17];
  const float* us   = (const float*)d_in[18];
  const float* cs   = (const float*)d_in[19];
  const float* bs   = (const float*)d_in[20];
  const float* gs   = (const float*)d_in[21];
  const float* bes  = (const float*)d_in[22];
  const float* Wc   = (const float*)d_in[23];
  const float* uc   = (const float*)d_in[24];
  const float* cc   = (const float*)d_in[25];
  const float* bc   = (const float*)d_in[26];
  const float* sWc  = (const float*)d_in[27];
  const float* sbc  = (const float*)d_in[28];
  const float* gc   = (const float*)d_in[29];
  const float* bec  = (const float*)d_in[30];
  const float* Wo   = (const float*)d_in[31];
  const float* uo   = (const float*)d_in[32];
  const float* co   = (const float*)d_in[33];
  const float* bo   = (const float*)d_in[34];
  const float* sWo  = (const float*)d_in[35];
  const float* sbo  = (const float*)d_in[36];

  const int N0 = in_sizes[0] / 4;
  const int nE0 = in_sizes[1] / 2;
  const int nE1 = in_sizes[2] / 2;
  const int nE2 = in_sizes[3] / 2;
  const int N1 = 5000, N2 = 1250;

  // ---- workspace layout ----
  float* fp = (float*)d_ws;
  auto alloc_f = [&](size_t n) { n = (n + 15) & ~(size_t)15; float* p = fp; fp += n; return p; };
  auto alloc_h = [&](size_t n) { return (u16*)alloc_f((n + 1) / 2); };
  u16*   Gy = alloc_h((size_t)N0 * 560);
  float* Gl = alloc_f((size_t)N0 * 4);
  float* Gs = alloc_f((size_t)N0 * CC);
  u16* a0A = alloc_h((size_t)N0 * HALF);
  u16* a0B = alloc_h((size_t)N0 * HALF);
  u16* a1A = alloc_h((size_t)N1 * HALF);
  u16* a1B = alloc_h((size_t)N1 * HALF);
  u16* a2A = alloc_h((size_t)N2 * HALF);
  u16* a2B = alloc_h((size_t)N2 * HALF);
  u16* xb  = alloc_h((size_t)N0 * 32);
  u16* Bp01 = alloc_h(P01);
  u16* Bpc0 = alloc_h(PCAT);
  u16* Bpc1 = alloc_h(PCAT);
  u16* Bpo  = alloc_h(PO);
  u16* Bps_all = alloc_h((size_t)10 * PS);
  u16* Bps[10];
  for (int i = 0; i < 10; ++i) Bps[i] = Bps_all + (size_t)i * PS;
  int* ipb = (int*)fp;
  auto alloc_i = [&](size_t n) { int* p = ipb; ipb += n; return p; };
  int* rp0  = alloc_i(N0 + 1);
  int* sl0  = alloc_i(nE0);
  int* rp1  = alloc_i(N1 + 1);
  int* sl1  = alloc_i(nE1);
  int* rp2  = alloc_i(N2 + 1);
  int* sl2  = alloc_i(nE2);
  int* rpc1 = alloc_i(N1 + 1);
  int* slc1 = alloc_i(N0);
  int* rpc2 = alloc_i(N2 + 1);
  int* slc2 = alloc_i(N1);
  int* cur0 = alloc_i(N0);
  int* cur1 = alloc_i(N1);
  int* cur2 = alloc_i(N2);
  int* cur3 = alloc_i(N1);
  int* cur4 = alloc_i(N2);
  const int curTot = N0 + N1 + N2 + N1 + N2;
  if ((size_t)((char*)ipb - (char*)d_ws) > ws_size) return;

  auto cdiv = [](int a, int b) { return (a + b - 1) / b; };

  // ---- CSR build: 4 launches ----
  k_zero_i32<<<cdiv(curTot, 256), 256, 0, stream>>>(cur0, curTot);
  {
    int tot = nE0 + nE1 + nE2 + N0 + N1;
    k_hist_all<<<cdiv(tot, 256), 256, 0, stream>>>(e0, nE0, e1, nE1, e2, nE2, cl1, N0, cl2, N1,
                                                   cur0, cur1, cur2, cur3, cur4);
    k_exscan5<<<5, 1024, 0, stream>>>(cur0, N0, rp0, cur1, N1, rp1, cur2, N2, rp2,
                                      cur3, N1, rpc1, cur4, N2, rpc2);
    k_scatter_all<<<cdiv(tot, 256), 256, 0, stream>>>(e0, nE0, e1, nE1, e2, nE2, cl1, N0, cl2, N1,
                                                      cur0, cur1, cur2, cur3, cur4,
                                                      sl0, sl1, sl2, slc1, slc2);
  }
  // ---- mega pack ----
  {
    int tot = P01 + 2 * PCAT + PO + 10 * PS + N0 * 32;
    k_pack_all<<<cdiv(tot, 256), 256, 0, stream>>>(W01, u01, sW01, Wc, uc, sWc, Wo, uo, sWo,
                                                   Ws, us, x, Bp01, Bpc0, Bpc1, Bpo,
                                                   Bps_all, xb, N0);
  }

  // conv driver
  auto do_conv = [&](const u16* A1, const u16* A2, const int* amap, int Kpad, int lda1,
                     const u16* Bp, int Mld, bool hasSkip, int n, const int* rp, const int* sl,
                     const float* cp, const float* bp, const float* gp, const float* bep,
                     const u16* skipA, const float* sbp, u16* outA) {
    dim3 grid(Mld / 64, cdiv(n, 128));
    k_gemm_mfma<<<grid, 256, 0, stream>>>(A1, A2, amap, Bp, Gy, Gl, Gs,
                                          560, hasSkip ? CC : 0, n, Kpad, lda1);
    k_agg<<<cdiv(n, 4), 256, 0, stream>>>(Gy, Gl, cp, bp, gp, bep, skipA, Gs, sbp,
                                          rp, sl, outA, n, 1);
  };

  auto ci  = [&](int i) { return cs + (size_t)i * HH; };
  auto bi  = [&](int i) { return bs + (size_t)i * CC; };
  auto gi  = [&](int i) { return gs + (size_t)i * CC; };
  auto bei = [&](int i) { return bes + (size_t)i * CC; };

  // conv01: K=4 (padded 32), GEMM skip
  do_conv(xb, nullptr, nullptr, 32, 32, Bp01, 704, true, N0, rp0, sl0,
          c01, b01, g01, be01, nullptr, sb01, a0A);
  // conv02 (identity skip) -> copy0 = a0B
  do_conv(a0A, nullptr, nullptr, 160, HALF, Bps[0], 576, false, N0, rp0, sl0,
          ci(0), bi(0), gi(0), bei(0), a0A, nullptr, a0B);
  // pool1
  k_pool<<<cdiv(N1, 4), 256, 0, stream>>>(a0B, rpc1, slc1, a1A, N1);
  // conv11, conv12 (copy1 = a1A after conv12)
  do_conv(a1A, nullptr, nullptr, 160, HALF, Bps[1], 576, false, N1, rp1, sl1,
          ci(1), bi(1), gi(1), bei(1), a1A, nullptr, a1B);
  do_conv(a1B, nullptr, nullptr, 160, HALF, Bps[2], 576, false, N1, rp1, sl1,
          ci(2), bi(2), gi(2), bei(2), a1B, nullptr, a1A);
  // pool2
  k_pool<<<cdiv(N2, 4), 256, 0, stream>>>(a1A, rpc2, slc2, a2A, N2);
  // conv21, conv22
  do_conv(a2A, nullptr, nullptr, 160, HALF, Bps[3], 576, false, N2, rp2, sl2,
          ci(3), bi(3), gi(3), bei(3), a2A, nullptr, a2B);
  do_conv(a2B, nullptr, nullptr, 160, HALF, Bps[4], 576, false, N2, rp2, sl2,
          ci(4), bi(4), gi(4), bei(4), a2B, nullptr, a2A);
  // conv13 on [unpool2(a2A) | a1A], GEMM skip
  do_conv(a2A, a1A, cl2, 320, HALF, Bpc0, 704, true, N1, rp1, sl1,
          cc, bc, gc, bec, nullptr, sbc, a1B);
  // conv14, conv15, conv16
  do_conv(a1B, nullptr, nullptr, 160, HALF, Bps[5], 576, false, N1, rp1, sl1,
          ci(5), bi(5), gi(5), bei(5), a1B, nullptr, a1A);
  do_conv(a1A, nullptr, nullptr, 160, HALF, Bps[6], 576, false, N1, rp1, sl1,
          ci(6), bi(6), gi(6), bei(6), a1A, nullptr, a1B);
  do_conv(a1B, nullptr, nullptr, 160, HALF, Bps[7], 576, false, N1, rp1, sl1,
          ci(7), bi(7), gi(7), bei(7), a1B, nullptr, a1A);
  // conv03 on [unpool1(a1A) | a0B], GEMM skip
  do_conv(a1A, a0B, cl1, 320, HALF, Bpc1, 704, true, N0, rp0, sl0,
          cc + HH, bc + CC, gc + CC, bec + CC, nullptr, sbc + CC, a0A);
  // conv04, conv05
  do_conv(a0A, nullptr, nullptr, 160, HALF, Bps[8], 576, false, N0, rp0, sl0,
          ci(8), bi(8), gi(8), bei(8), a0A, nullptr, a0B);
  do_conv(a0B, nullptr, nullptr, 160, HALF, Bps[9], 576, false, N0, rp0, sl0,
          ci(9), bi(9), gi(9), bei(9), a0B, nullptr, a0A);
  // conv06: 140 -> 1
  {
    dim3 grid(1, cdiv(N0, 128));
    k_gemm_mfma<<<grid, 256, 0, stream>>>(a0A, nullptr, nullptr, Bpo, Gy, Gl, Gs,
                                          4, 1, N0, 160, HALF);
    k_out<<<cdiv(N0, 4), 256, 0, stream>>>(Gy, Gl, co, bo, Gs, sbo, rp0, sl0, (float*)d_out, N0);
  }
}